// Round 3
// baseline (1085.229 us; speedup 1.0000x reference)
//
#include <hip/hip_runtime.h>
#include <hip/hip_bf16.h>

#define D 128

// ---------------- setup kernels ----------------

__global__ void k_zero(int* __restrict__ p, int n) {
    int i = blockIdx.x * 256 + threadIdx.x;
    if (i < n) p[i] = 0;
}

__global__ void k_count(const int* __restrict__ dst, int* __restrict__ cnt, int e) {
    int i = blockIdx.x * 256 + threadIdx.x;
    if (i < e) atomicAdd(&cnt[dst[i]], 1);
}

// ---- hierarchical scan (+ fused dinv): A) block reduce, B) scan partials, C) rescan

__global__ __launch_bounds__(256) void k_scanA(const int* __restrict__ cnt,
                                               int* __restrict__ partials,
                                               float* __restrict__ dinv, int n) {
    __shared__ int s[256];
    int b = blockIdx.x, t = threadIdx.x;
    int i0 = b * 512 + t * 2;
    int v = 0;
    if (i0 < n) {
        int c0 = cnt[i0];
        v += c0;
        dinv[i0] = 1.0f / sqrtf((float)(c0 + 2));
    }
    if (i0 + 1 < n) {
        int c1 = cnt[i0 + 1];
        v += c1;
        dinv[i0 + 1] = 1.0f / sqrtf((float)(c1 + 2));
    }
    s[t] = v;
    __syncthreads();
    for (int off = 128; off > 0; off >>= 1) {
        if (t < off) s[t] += s[t + off];
        __syncthreads();
    }
    if (t == 0) partials[b] = s[0];
}

__global__ __launch_bounds__(512) void k_scanB(const int* __restrict__ partials,
                                               int* __restrict__ base,
                                               int* __restrict__ off_n, int nb) {
    __shared__ int s[512];
    int t = threadIdx.x;
    int v = (t < nb) ? partials[t] : 0;
    s[t] = v;
    __syncthreads();
    for (int off = 1; off < 512; off <<= 1) {
        int x = (t >= off) ? s[t - off] : 0;
        __syncthreads();
        s[t] += x;
        __syncthreads();
    }
    if (t < nb) base[t] = s[t] - v;          // exclusive
    if (t == nb - 1) off_n[0] = s[t];        // total = offsets[N]
}

__global__ __launch_bounds__(256) void k_scanC(const int* __restrict__ cnt,
                                               const int* __restrict__ base,
                                               int* __restrict__ offsets,
                                               int* __restrict__ cursor, int n) {
    __shared__ int s[256];
    int b = blockIdx.x, t = threadIdx.x;
    int i0 = b * 512 + t * 2;
    int v0 = (i0 < n) ? cnt[i0] : 0;
    int v1 = (i0 + 1 < n) ? cnt[i0 + 1] : 0;
    int sum = v0 + v1;
    s[t] = sum;
    __syncthreads();
    for (int off = 1; off < 256; off <<= 1) {
        int x = (t >= off) ? s[t - off] : 0;
        __syncthreads();
        s[t] += x;
        __syncthreads();
    }
    int excl = s[t] - sum + base[b];
    if (i0 < n) { offsets[i0] = excl; cursor[i0] = excl; }
    if (i0 + 1 < n) { offsets[i0 + 1] = excl + v0; cursor[i0 + 1] = excl + v0; }
}

// CSR entry = src node only (4B scatter; norm recomputed from L2-resident dinv)
__global__ void k_fill(const int* __restrict__ src, const int* __restrict__ dst,
                       int* __restrict__ cursor, int* __restrict__ csr, int e) {
    int i = blockIdx.x * 256 + threadIdx.x;
    if (i < e) {
        int s = src[i];
        int d = dst[i];
        int pos = atomicAdd(&cursor[d], 1);
        csr[pos] = s;
    }
}

// ---------------- bias-correction machinery (tiny) ----------------
// out = (A^5 x)(W1 W2^4) + b2 + sum_{j=1..3}(A^j 1)(b2 W2^j) + (A^4 1)(b1 W2^4)

// sparse matvec: vout = A vin; vin==nullptr means vin = ones
__global__ void k_spmv(const int* __restrict__ csr, const int* __restrict__ offsets,
                       const float* __restrict__ dinv, const float* __restrict__ vin,
                       float* __restrict__ vout, int n) {
    int i = blockIdx.x * 256 + threadIdx.x;
    if (i >= n) return;
    float di = dinv[i];
    int e1 = offsets[i + 1];
    float acc;
    if (vin) {
        acc = 2.0f * di * vin[i];
        for (int e = offsets[i]; e < e1; e++) {
            int s = csr[e];
            acc += dinv[s] * vin[s];
        }
    } else {
        acc = 2.0f * di;
        for (int e = offsets[i]; e < e1; e++) acc += dinv[csr[e]];
    }
    vout[i] = di * acc;
}

// whole bias row-vector chain in one block:
// cmat rows: 0=b2, 1=b2W2, 2=b2W2^2, 3=b2W2^3, 4=b1W2^4
__global__ __launch_bounds__(128) void k_biaschain(const float* __restrict__ b1,
                                                   const float* __restrict__ b2,
                                                   const float* __restrict__ W2,
                                                   float* __restrict__ cmat) {
    __shared__ float s[128];
    int d = threadIdx.x;
    float v = b2[d];
    cmat[d] = v;
    for (int j = 1; j <= 3; j++) {
        s[d] = v;
        __syncthreads();
        float acc = 0.0f;
#pragma unroll 8
        for (int k = 0; k < 128; k++) acc += s[k] * W2[k * 128 + d];
        v = acc;
        cmat[j * 128 + d] = v;
        __syncthreads();
    }
    v = b1[d];
    for (int j = 0; j < 4; j++) {
        s[d] = v;
        __syncthreads();
        float acc = 0.0f;
#pragma unroll 8
        for (int k = 0; k < 128; k++) acc += s[k] * W2[k * 128 + d];
        v = acc;
        __syncthreads();
    }
    cmat[4 * 128 + d] = v;
}

// small 128x128 @ 128x128: C[r][d] = sum_k A[r][k] B[k][d]
__global__ __launch_bounds__(128) void k_wmm(const float* __restrict__ A,
                                             const float* __restrict__ B,
                                             float* __restrict__ Cm) {
    __shared__ float a[128];
    int r = blockIdx.x, d = threadIdx.x;
    a[d] = A[r * 128 + d];
    __syncthreads();
    float acc = 0.0f;
#pragma unroll 8
    for (int k = 0; k < 128; k++) acc += a[k] * B[k * 128 + d];
    Cm[r * 128 + d] = acc;
}

// ---------------- matmul: O = H @ W + const-bias + U C  (rank-4 + const) ----
__global__ __launch_bounds__(256) void k_matmul(const float* __restrict__ H,
                                                const float* __restrict__ W,
                                                float* __restrict__ O,
                                                const float* __restrict__ ucol,  // [4][nrows]
                                                const float* __restrict__ cmat,  // [5][128]
                                                int nrows) {
    __shared__ float Ws[32 * D];    // Ws[k][c]
    __shared__ float HsT[32 * 128]; // HsT[k][r]
    const int t = threadIdx.x;
    const int row0 = blockIdx.x * 128;
    const int tx = t & 15;    // col group (8 cols)
    const int ty = t >> 4;    // row group (8 rows)
    const int r_st = t & 127;
    const int kb = (t >> 7) * 16;   // 0 or 16
    const int gr = row0 + r_st;
    const bool grok = (gr < nrows);

    float acc[8][8];
    // constant bias row (b2)
    {
        float bc[8];
#pragma unroll
        for (int j = 0; j < 8; j++) bc[j] = cmat[tx * 8 + j];
#pragma unroll
        for (int i = 0; i < 8; i++)
#pragma unroll
            for (int j = 0; j < 8; j++) acc[i][j] = bc[j];
    }
    // rank-4 correction: ucol[tt] pairs with cmat row tt+1
#pragma unroll
    for (int tt = 0; tt < 4; tt++) {
        float c0 = cmat[(tt + 1) * D + tx * 8 + 0], c1 = cmat[(tt + 1) * D + tx * 8 + 1];
        float c2 = cmat[(tt + 1) * D + tx * 8 + 2], c3 = cmat[(tt + 1) * D + tx * 8 + 3];
        float c4 = cmat[(tt + 1) * D + tx * 8 + 4], c5 = cmat[(tt + 1) * D + tx * 8 + 5];
        float c6 = cmat[(tt + 1) * D + tx * 8 + 6], c7 = cmat[(tt + 1) * D + tx * 8 + 7];
#pragma unroll
        for (int i = 0; i < 8; i++) {
            int gr2 = row0 + ty * 8 + i;
            if (gr2 < nrows) {
                float ut = ucol[(size_t)tt * nrows + gr2];
                acc[i][0] += ut * c0; acc[i][1] += ut * c1;
                acc[i][2] += ut * c2; acc[i][3] += ut * c3;
                acc[i][4] += ut * c4; acc[i][5] += ut * c5;
                acc[i][6] += ut * c6; acc[i][7] += ut * c7;
            }
        }
    }

    float4 w0, w1, w2, w3, h0, h1, h2, h3;
    {   // prologue: load chunk 0
        const float4* W4 = (const float4*)W;
        w0 = W4[t]; w1 = W4[t + 256]; w2 = W4[t + 512]; w3 = W4[t + 768];
        if (grok) {
            const float4* Hp = (const float4*)(H + (size_t)gr * D + kb);
            h0 = Hp[0]; h1 = Hp[1]; h2 = Hp[2]; h3 = Hp[3];
        } else {
            h0 = h1 = h2 = h3 = make_float4(0.f, 0.f, 0.f, 0.f);
        }
    }

    for (int kc = 0; kc < D; kc += 32) {
        {
            float4* Ws4 = (float4*)Ws;
            Ws4[t] = w0; Ws4[t + 256] = w1; Ws4[t + 512] = w2; Ws4[t + 768] = w3;
            float vals[16];
            *(float4*)&vals[0]  = h0;
            *(float4*)&vals[4]  = h1;
            *(float4*)&vals[8]  = h2;
            *(float4*)&vals[12] = h3;
#pragma unroll
            for (int j = 0; j < 16; j++) HsT[(kb + j) * 128 + r_st] = vals[j];
        }
        __syncthreads();

        if (kc + 32 < D) {
            const float4* W4 = (const float4*)(W + (kc + 32) * D);
            w0 = W4[t]; w1 = W4[t + 256]; w2 = W4[t + 512]; w3 = W4[t + 768];
            if (grok) {
                const float4* Hp = (const float4*)(H + (size_t)gr * D + (kc + 32) + kb);
                h0 = Hp[0]; h1 = Hp[1]; h2 = Hp[2]; h3 = Hp[3];
            }
        }

#pragma unroll 8
        for (int k = 0; k < 32; k++) {
            float4 a0 = *(const float4*)&HsT[k * 128 + ty * 8];
            float4 a1 = *(const float4*)&HsT[k * 128 + ty * 8 + 4];
            float4 b0 = *(const float4*)&Ws[k * D + tx * 8];
            float4 b1 = *(const float4*)&Ws[k * D + tx * 8 + 4];
            float ar[8] = {a0.x, a0.y, a0.z, a0.w, a1.x, a1.y, a1.z, a1.w};
            float br[8] = {b0.x, b0.y, b0.z, b0.w, b1.x, b1.y, b1.z, b1.w};
#pragma unroll
            for (int i = 0; i < 8; i++)
#pragma unroll
                for (int j = 0; j < 8; j++) acc[i][j] += ar[i] * br[j];
        }
        __syncthreads();
    }
#pragma unroll
    for (int i = 0; i < 8; i++) {
        int gr2 = row0 + ty * 8 + i;
        if (gr2 < nrows) {
            float4* Op = (float4*)(O + (size_t)gr2 * D + tx * 8);
            Op[0] = make_float4(acc[i][0], acc[i][1], acc[i][2], acc[i][3]);
            Op[1] = make_float4(acc[i][4], acc[i][5], acc[i][6], acc[i][7]);
        }
    }
}

// ---------------- gather: O = A T ----------------
// one wave per node; half-wave per edge row (32 lanes x float4 = 512B);
// 16-edge main loop = 8 independent 1KiB dual-row loads in flight.
// dinv[dst] factored out: acc_final = dn * (2*dn*T[node] + sum dinv[s]*T[s])
__global__ __launch_bounds__(256) void k_gather(const float* __restrict__ T,
                                                const int* __restrict__ csr,
                                                const int* __restrict__ offsets,
                                                const float* __restrict__ dinv,
                                                float* __restrict__ O, int n) {
    int node = blockIdx.x * 4 + (threadIdx.x >> 6);
    if (node >= n) return;
    int lane = threadIdx.x & 63;
    int half = lane >> 5;            // 0 or 1
    int c = (lane & 31) << 2;        // col base (float4)
    const float* Tc = T + c;
    const float dn = dinv[node];

    float ax = 0.f, ay = 0.f, az = 0.f, aw = 0.f;
    if (half == 0) {
        float sw = 2.0f * dn;
        float4 v = *(const float4*)(Tc + (size_t)node * D);
        ax = sw * v.x; ay = sw * v.y; az = sw * v.z; aw = sw * v.w;
    }

    int e = offsets[node];
    const int e1 = offsets[node + 1];

    for (; e + 16 <= e1; e += 16) {
        int s0 = csr[e + half +  0], s1 = csr[e + half +  2];
        int s2 = csr[e + half +  4], s3 = csr[e + half +  6];
        int s4 = csr[e + half +  8], s5 = csr[e + half + 10];
        int s6 = csr[e + half + 12], s7 = csr[e + half + 14];
        float4 v0 = *(const float4*)(Tc + (size_t)s0 * D);
        float4 v1 = *(const float4*)(Tc + (size_t)s1 * D);
        float4 v2 = *(const float4*)(Tc + (size_t)s2 * D);
        float4 v3 = *(const float4*)(Tc + (size_t)s3 * D);
        float4 v4 = *(const float4*)(Tc + (size_t)s4 * D);
        float4 v5 = *(const float4*)(Tc + (size_t)s5 * D);
        float4 v6 = *(const float4*)(Tc + (size_t)s6 * D);
        float4 v7 = *(const float4*)(Tc + (size_t)s7 * D);
        float w0 = dinv[s0], w1 = dinv[s1], w2 = dinv[s2], w3 = dinv[s3];
        float w4 = dinv[s4], w5 = dinv[s5], w6 = dinv[s6], w7 = dinv[s7];
        ax += w0 * v0.x; ay += w0 * v0.y; az += w0 * v0.z; aw += w0 * v0.w;
        ax += w1 * v1.x; ay += w1 * v1.y; az += w1 * v1.z; aw += w1 * v1.w;
        ax += w2 * v2.x; ay += w2 * v2.y; az += w2 * v2.z; aw += w2 * v2.w;
        ax += w3 * v3.x; ay += w3 * v3.y; az += w3 * v3.z; aw += w3 * v3.w;
        ax += w4 * v4.x; ay += w4 * v4.y; az += w4 * v4.z; aw += w4 * v4.w;
        ax += w5 * v5.x; ay += w5 * v5.y; az += w5 * v5.z; aw += w5 * v5.w;
        ax += w6 * v6.x; ay += w6 * v6.y; az += w6 * v6.z; aw += w6 * v6.w;
        ax += w7 * v7.x; ay += w7 * v7.y; az += w7 * v7.z; aw += w7 * v7.w;
    }
    for (; e + 8 <= e1; e += 8) {
        int s0 = csr[e + half + 0], s1 = csr[e + half + 2];
        int s2 = csr[e + half + 4], s3 = csr[e + half + 6];
        float4 v0 = *(const float4*)(Tc + (size_t)s0 * D);
        float4 v1 = *(const float4*)(Tc + (size_t)s1 * D);
        float4 v2 = *(const float4*)(Tc + (size_t)s2 * D);
        float4 v3 = *(const float4*)(Tc + (size_t)s3 * D);
        float w0 = dinv[s0], w1 = dinv[s1], w2 = dinv[s2], w3 = dinv[s3];
        ax += w0 * v0.x; ay += w0 * v0.y; az += w0 * v0.z; aw += w0 * v0.w;
        ax += w1 * v1.x; ay += w1 * v1.y; az += w1 * v1.z; aw += w1 * v1.w;
        ax += w2 * v2.x; ay += w2 * v2.y; az += w2 * v2.z; aw += w2 * v2.w;
        ax += w3 * v3.x; ay += w3 * v3.y; az += w3 * v3.z; aw += w3 * v3.w;
    }
    for (; e + 2 <= e1; e += 2) {
        int s0 = csr[e + half];
        float4 v0 = *(const float4*)(Tc + (size_t)s0 * D);
        float w0 = dinv[s0];
        ax += w0 * v0.x; ay += w0 * v0.y; az += w0 * v0.z; aw += w0 * v0.w;
    }
    if (e < e1 && half == 0) {
        int s0 = csr[e];
        float4 v0 = *(const float4*)(Tc + (size_t)s0 * D);
        float w0 = dinv[s0];
        ax += w0 * v0.x; ay += w0 * v0.y; az += w0 * v0.z; aw += w0 * v0.w;
    }

    ax += __shfl_xor(ax, 32, 64);
    ay += __shfl_xor(ay, 32, 64);
    az += __shfl_xor(az, 32, 64);
    aw += __shfl_xor(aw, 32, 64);

    if (half == 0) {
        *(float4*)(O + (size_t)node * D + c) =
            make_float4(dn * ax, dn * ay, dn * az, dn * aw);
    }
}

// ---------------- launch ----------------
// out = (A^5 x)(W1 W2^4) + b2 + sum_{j=1..3}(A^j 1)(b2 W2^j) + (A^4 1)(b1 W2^4)

extern "C" void kernel_launch(void* const* d_in, const int* in_sizes, int n_in,
                              void* d_out, int out_size, void* d_ws, size_t ws_size,
                              hipStream_t stream) {
    const float* x  = (const float*)d_in[0];
    const int*   ei = (const int*)d_in[1];
    const float* W1 = (const float*)d_in[2];
    const float* b1 = (const float*)d_in[3];
    const float* W2 = (const float*)d_in[4];
    const float* b2 = (const float*)d_in[5];
    const int N = in_sizes[0] / D;
    const int E = in_sizes[1] / 2;
    float* out = (float*)d_out;

    char* ws = (char*)d_ws;
    size_t woff = 0;
    auto alloc = [&](size_t bytes) -> void* {
        void* p = ws + woff;
        woff = (woff + bytes + 15) & ~(size_t)15;
        return p;
    };
    float* T        = (float*)alloc((size_t)N * D * sizeof(float));
    int*   cnt      = (int*)  alloc((size_t)N * sizeof(int));
    int*   offsets  = (int*)  alloc((size_t)(N + 1) * sizeof(int));
    int*   cursor   = (int*)  alloc((size_t)N * sizeof(int));
    float* dinv     = (float*)alloc((size_t)N * sizeof(float));
    int*   csr      = (int*)  alloc((size_t)E * sizeof(int));
    int*   partials = (int*)  alloc(1024 * sizeof(int));
    int*   base     = (int*)  alloc(1024 * sizeof(int));
    float* ucol     = (float*)alloc((size_t)4 * N * sizeof(float));   // [4][N]: A^j 1, j=1..4
    float* cmat     = (float*)alloc(5 * 128 * sizeof(float));         // [5][128]
    float* Wa       = (float*)alloc(128 * 128 * sizeof(float));
    float* Wb       = (float*)alloc(128 * 128 * sizeof(float));
    (void)ws_size; (void)n_in; (void)out_size;

    const int* e_src = ei;
    const int* e_dst = ei + E;
    const int NB = (N + 511) / 512;

    // --- CSR build (+ dinv fused into scanA) ---
    k_zero<<<(N + 255) / 256, 256, 0, stream>>>(cnt, N);
    k_count<<<(E + 255) / 256, 256, 0, stream>>>(e_dst, cnt, E);
    k_scanA<<<NB, 256, 0, stream>>>(cnt, partials, dinv, N);
    k_scanB<<<1, 512, 0, stream>>>(partials, base, offsets + N, NB);
    k_scanC<<<NB, 256, 0, stream>>>(cnt, base, offsets, cursor, N);
    k_fill<<<(E + 255) / 256, 256, 0, stream>>>(e_src, e_dst, cursor, csr, E);

    // --- g = A^5 x, ping-pong T <-> out ---
    const int GG = (N + 3) / 4;
    k_gather<<<GG, 256, 0, stream>>>(x,   csr, offsets, dinv, T,   N);
    k_gather<<<GG, 256, 0, stream>>>(T,   csr, offsets, dinv, out, N);
    k_gather<<<GG, 256, 0, stream>>>(out, csr, offsets, dinv, T,   N);
    k_gather<<<GG, 256, 0, stream>>>(T,   csr, offsets, dinv, out, N);
    k_gather<<<GG, 256, 0, stream>>>(out, csr, offsets, dinv, T,   N);

    // --- degree vectors: ucol rows = A^j 1, j=1..4 (first call: vin = ones) ---
    k_spmv<<<(N + 255) / 256, 256, 0, stream>>>(csr, offsets, dinv, nullptr,      ucol,         N);
    k_spmv<<<(N + 255) / 256, 256, 0, stream>>>(csr, offsets, dinv, ucol,         ucol + N,     N);
    k_spmv<<<(N + 255) / 256, 256, 0, stream>>>(csr, offsets, dinv, ucol + N,     ucol + 2 * N, N);
    k_spmv<<<(N + 255) / 256, 256, 0, stream>>>(csr, offsets, dinv, ucol + 2 * N, ucol + 3 * N, N);

    // --- weight chain: Wtot = W1 W2^4 (Wb holds result) ---
    k_wmm<<<128, 128, 0, stream>>>(W1, W2, Wa);
    k_wmm<<<128, 128, 0, stream>>>(Wa, W2, Wb);
    k_wmm<<<128, 128, 0, stream>>>(Wb, W2, Wa);
    k_wmm<<<128, 128, 0, stream>>>(Wa, W2, Wb);

    // --- bias rows in one block ---
    k_biaschain<<<1, 128, 0, stream>>>(b1, b2, W2, cmat);

    // --- out = T @ Wtot + b2 + U C ---
    k_matmul<<<(N + 127) / 128, 256, 0, stream>>>(T, Wb, out, ucol, cmat, N);
}

// Round 4
// 939.146 us; speedup vs baseline: 1.1555x; 1.1555x over previous
//
#include <hip/hip_runtime.h>
#include <hip/hip_bf16.h>

#define D 128

// ---------------- setup kernels ----------------

__global__ void k_zero(int* __restrict__ p, int n) {
    int i = blockIdx.x * 256 + threadIdx.x;
    if (i < n) p[i] = 0;
}

// count degrees AND record each edge's rank within its destination
// (rank + exclusive-scan offsets => unique dense CSR slot, no atomic in fill)
__global__ void k_count(const int* __restrict__ dst, int* __restrict__ cnt,
                        int* __restrict__ rank, int e) {
    int i = blockIdx.x * 256 + threadIdx.x;
    if (i < e) rank[i] = atomicAdd(&cnt[dst[i]], 1);
}

// ---- hierarchical scan (+ fused dinv): A) block reduce, B) scan partials, C) rescan

__global__ __launch_bounds__(256) void k_scanA(const int* __restrict__ cnt,
                                               int* __restrict__ partials,
                                               float* __restrict__ dinv, int n) {
    __shared__ int s[256];
    int b = blockIdx.x, t = threadIdx.x;
    int i0 = b * 512 + t * 2;
    int v = 0;
    if (i0 < n) {
        int c0 = cnt[i0];
        v += c0;
        dinv[i0] = 1.0f / sqrtf((float)(c0 + 2));
    }
    if (i0 + 1 < n) {
        int c1 = cnt[i0 + 1];
        v += c1;
        dinv[i0 + 1] = 1.0f / sqrtf((float)(c1 + 2));
    }
    s[t] = v;
    __syncthreads();
    for (int off = 128; off > 0; off >>= 1) {
        if (t < off) s[t] += s[t + off];
        __syncthreads();
    }
    if (t == 0) partials[b] = s[0];
}

__global__ __launch_bounds__(512) void k_scanB(const int* __restrict__ partials,
                                               int* __restrict__ base,
                                               int* __restrict__ off_n, int nb) {
    __shared__ int s[512];
    int t = threadIdx.x;
    int v = (t < nb) ? partials[t] : 0;
    s[t] = v;
    __syncthreads();
    for (int off = 1; off < 512; off <<= 1) {
        int x = (t >= off) ? s[t - off] : 0;
        __syncthreads();
        s[t] += x;
        __syncthreads();
    }
    if (t < nb) base[t] = s[t] - v;          // exclusive
    if (t == nb - 1) off_n[0] = s[t];        // total = offsets[N]
}

__global__ __launch_bounds__(256) void k_scanC(const int* __restrict__ cnt,
                                               const int* __restrict__ base,
                                               int* __restrict__ offsets, int n) {
    __shared__ int s[256];
    int b = blockIdx.x, t = threadIdx.x;
    int i0 = b * 512 + t * 2;
    int v0 = (i0 < n) ? cnt[i0] : 0;
    int v1 = (i0 + 1 < n) ? cnt[i0 + 1] : 0;
    int sum = v0 + v1;
    s[t] = sum;
    __syncthreads();
    for (int off = 1; off < 256; off <<= 1) {
        int x = (t >= off) ? s[t - off] : 0;
        __syncthreads();
        s[t] += x;
        __syncthreads();
    }
    int excl = s[t] - sum + base[b];
    if (i0 < n) offsets[i0] = excl;
    if (i0 + 1 < n) offsets[i0 + 1] = excl + v0;
}

// packed CSR entry: .x = src node, .y = bit-cast float norm. NO atomic:
// slot = offsets[dst] + precomputed rank. Streaming reads + scatter store only.
__global__ void k_fill(const int* __restrict__ src, const int* __restrict__ dst,
                       const int* __restrict__ rank, const int* __restrict__ offsets,
                       const float* __restrict__ dinv, int2* __restrict__ csr, int e) {
    int i = blockIdx.x * 256 + threadIdx.x;
    if (i < e) {
        int s = src[i];
        int d = dst[i];
        int pos = offsets[d] + rank[i];
        csr[pos] = make_int2(s, __float_as_int(dinv[s] * dinv[d]));
    }
}

// ---------------- bias-correction machinery (tiny) ----------------
// out = (A^5 x)(W1 W2^4) + b2 + sum_{j=1..3}(A^j 1)(b2 W2^j) + (A^4 1)(b1 W2^4)

// sparse matvec: vout = A vin; vin==nullptr means vin = ones
__global__ void k_spmv(const int2* __restrict__ csr, const int* __restrict__ offsets,
                       const float* __restrict__ dinv, const float* __restrict__ vin,
                       float* __restrict__ vout, int n) {
    int i = blockIdx.x * 256 + threadIdx.x;
    if (i >= n) return;
    float di = dinv[i];
    int e1 = offsets[i + 1];
    float acc;
    if (vin) {
        acc = 2.0f * di * di * vin[i];
        for (int e = offsets[i]; e < e1; e++) {
            int2 p = csr[e];
            acc += __int_as_float(p.y) * vin[p.x];
        }
    } else {
        acc = 2.0f * di * di;
        for (int e = offsets[i]; e < e1; e++) acc += __int_as_float(csr[e].y);
    }
    vout[i] = acc;
}

// bias row-vector chain in one block:
// cmat rows: 0=b2, 1=b2W2, 2=b2W2^2, 3=b2W2^3, 4=b1W2^4 (uses precomputed W4)
__global__ __launch_bounds__(128) void k_biaschain(const float* __restrict__ b1,
                                                   const float* __restrict__ b2,
                                                   const float* __restrict__ W2,
                                                   const float* __restrict__ W4,
                                                   float* __restrict__ cmat) {
    __shared__ float s[128];
    int d = threadIdx.x;
    float v = b2[d];
    cmat[d] = v;
    for (int j = 1; j <= 3; j++) {
        s[d] = v;
        __syncthreads();
        float acc = 0.0f;
#pragma unroll 8
        for (int k = 0; k < 128; k++) acc += s[k] * W2[k * 128 + d];
        v = acc;
        cmat[j * 128 + d] = v;
        __syncthreads();
    }
    s[d] = b1[d];
    __syncthreads();
    float acc = 0.0f;
#pragma unroll 8
    for (int k = 0; k < 128; k++) acc += s[k] * W4[k * 128 + d];
    cmat[4 * 128 + d] = acc;
}

// small 128x128 @ 128x128: C[r][d] = sum_k A[r][k] B[k][d]
__global__ __launch_bounds__(128) void k_wmm(const float* __restrict__ A,
                                             const float* __restrict__ B,
                                             float* __restrict__ Cm) {
    __shared__ float a[128];
    int r = blockIdx.x, d = threadIdx.x;
    a[d] = A[r * 128 + d];
    __syncthreads();
    float acc = 0.0f;
#pragma unroll 8
    for (int k = 0; k < 128; k++) acc += a[k] * B[k * 128 + d];
    Cm[r * 128 + d] = acc;
}

// ---------------- matmul: O = H @ W + const-bias + U C  (rank-4 + const) ----
__global__ __launch_bounds__(256) void k_matmul(const float* __restrict__ H,
                                                const float* __restrict__ W,
                                                float* __restrict__ O,
                                                const float* __restrict__ ucol,  // [4][nrows]
                                                const float* __restrict__ cmat,  // [5][128]
                                                int nrows) {
    __shared__ float Ws[32 * D];    // Ws[k][c]
    __shared__ float HsT[32 * 128]; // HsT[k][r]
    const int t = threadIdx.x;
    const int row0 = blockIdx.x * 128;
    const int tx = t & 15;    // col group (8 cols)
    const int ty = t >> 4;    // row group (8 rows)
    const int r_st = t & 127;
    const int kb = (t >> 7) * 16;   // 0 or 16
    const int gr = row0 + r_st;
    const bool grok = (gr < nrows);

    float acc[8][8];
    // constant bias row (b2)
    {
        float bc[8];
#pragma unroll
        for (int j = 0; j < 8; j++) bc[j] = cmat[tx * 8 + j];
#pragma unroll
        for (int i = 0; i < 8; i++)
#pragma unroll
            for (int j = 0; j < 8; j++) acc[i][j] = bc[j];
    }
    // rank-4 correction: ucol[tt] pairs with cmat row tt+1
#pragma unroll
    for (int tt = 0; tt < 4; tt++) {
        float c0 = cmat[(tt + 1) * D + tx * 8 + 0], c1 = cmat[(tt + 1) * D + tx * 8 + 1];
        float c2 = cmat[(tt + 1) * D + tx * 8 + 2], c3 = cmat[(tt + 1) * D + tx * 8 + 3];
        float c4 = cmat[(tt + 1) * D + tx * 8 + 4], c5 = cmat[(tt + 1) * D + tx * 8 + 5];
        float c6 = cmat[(tt + 1) * D + tx * 8 + 6], c7 = cmat[(tt + 1) * D + tx * 8 + 7];
#pragma unroll
        for (int i = 0; i < 8; i++) {
            int gr2 = row0 + ty * 8 + i;
            if (gr2 < nrows) {
                float ut = ucol[(size_t)tt * nrows + gr2];
                acc[i][0] += ut * c0; acc[i][1] += ut * c1;
                acc[i][2] += ut * c2; acc[i][3] += ut * c3;
                acc[i][4] += ut * c4; acc[i][5] += ut * c5;
                acc[i][6] += ut * c6; acc[i][7] += ut * c7;
            }
        }
    }

    float4 w0, w1, w2, w3, h0, h1, h2, h3;
    {   // prologue: load chunk 0
        const float4* W4p = (const float4*)W;
        w0 = W4p[t]; w1 = W4p[t + 256]; w2 = W4p[t + 512]; w3 = W4p[t + 768];
        if (grok) {
            const float4* Hp = (const float4*)(H + (size_t)gr * D + kb);
            h0 = Hp[0]; h1 = Hp[1]; h2 = Hp[2]; h3 = Hp[3];
        } else {
            h0 = h1 = h2 = h3 = make_float4(0.f, 0.f, 0.f, 0.f);
        }
    }

    for (int kc = 0; kc < D; kc += 32) {
        {
            float4* Ws4 = (float4*)Ws;
            Ws4[t] = w0; Ws4[t + 256] = w1; Ws4[t + 512] = w2; Ws4[t + 768] = w3;
            float vals[16];
            *(float4*)&vals[0]  = h0;
            *(float4*)&vals[4]  = h1;
            *(float4*)&vals[8]  = h2;
            *(float4*)&vals[12] = h3;
#pragma unroll
            for (int j = 0; j < 16; j++) HsT[(kb + j) * 128 + r_st] = vals[j];
        }
        __syncthreads();

        if (kc + 32 < D) {
            const float4* W4p = (const float4*)(W + (kc + 32) * D);
            w0 = W4p[t]; w1 = W4p[t + 256]; w2 = W4p[t + 512]; w3 = W4p[t + 768];
            if (grok) {
                const float4* Hp = (const float4*)(H + (size_t)gr * D + (kc + 32) + kb);
                h0 = Hp[0]; h1 = Hp[1]; h2 = Hp[2]; h3 = Hp[3];
            }
        }

#pragma unroll 8
        for (int k = 0; k < 32; k++) {
            float4 a0 = *(const float4*)&HsT[k * 128 + ty * 8];
            float4 a1 = *(const float4*)&HsT[k * 128 + ty * 8 + 4];
            float4 b0 = *(const float4*)&Ws[k * D + tx * 8];
            float4 b1 = *(const float4*)&Ws[k * D + tx * 8 + 4];
            float ar[8] = {a0.x, a0.y, a0.z, a0.w, a1.x, a1.y, a1.z, a1.w};
            float br[8] = {b0.x, b0.y, b0.z, b0.w, b1.x, b1.y, b1.z, b1.w};
#pragma unroll
            for (int i = 0; i < 8; i++)
#pragma unroll
                for (int j = 0; j < 8; j++) acc[i][j] += ar[i] * br[j];
        }
        __syncthreads();
    }
#pragma unroll
    for (int i = 0; i < 8; i++) {
        int gr2 = row0 + ty * 8 + i;
        if (gr2 < nrows) {
            float4* Op = (float4*)(O + (size_t)gr2 * D + tx * 8);
            Op[0] = make_float4(acc[i][0], acc[i][1], acc[i][2], acc[i][3]);
            Op[1] = make_float4(acc[i][4], acc[i][5], acc[i][6], acc[i][7]);
        }
    }
}

// ---------------- gather: O = A T ----------------
// one wave per node; half-wave per edge row (32 lanes x float4 = 512B);
// 8-edge main loop = 4 independent 1KiB dual-row loads in flight (VGPR 24,
// ~10 waves/SIMD — round-3's 16-deep variant halved occupancy and regressed).
__global__ __launch_bounds__(256) void k_gather(const float* __restrict__ T,
                                                const int2* __restrict__ csr,
                                                const int* __restrict__ offsets,
                                                const float* __restrict__ dinv,
                                                float* __restrict__ O, int n) {
    int node = blockIdx.x * 4 + (threadIdx.x >> 6);
    if (node >= n) return;
    int lane = threadIdx.x & 63;
    int half = lane >> 5;            // 0 or 1
    int c = (lane & 31) << 2;        // col base (float4)
    const float* Tc = T + c;

    float ax = 0.f, ay = 0.f, az = 0.f, aw = 0.f;
    if (half == 0) {
        float di = dinv[node];
        float sw = 2.0f * di * di;
        float4 v = *(const float4*)(Tc + (size_t)node * D);
        ax = sw * v.x; ay = sw * v.y; az = sw * v.z; aw = sw * v.w;
    }

    int e = offsets[node];
    const int e1 = offsets[node + 1];

    for (; e + 8 <= e1; e += 8) {
        int2 p0 = csr[e + half];
        int2 p1 = csr[e + 2 + half];
        int2 p2 = csr[e + 4 + half];
        int2 p3 = csr[e + 6 + half];
        float4 v0 = *(const float4*)(Tc + (size_t)p0.x * D);
        float4 v1 = *(const float4*)(Tc + (size_t)p1.x * D);
        float4 v2 = *(const float4*)(Tc + (size_t)p2.x * D);
        float4 v3 = *(const float4*)(Tc + (size_t)p3.x * D);
        float w0 = __int_as_float(p0.y), w1 = __int_as_float(p1.y);
        float w2 = __int_as_float(p2.y), w3 = __int_as_float(p3.y);
        ax += w0 * v0.x; ay += w0 * v0.y; az += w0 * v0.z; aw += w0 * v0.w;
        ax += w1 * v1.x; ay += w1 * v1.y; az += w1 * v1.z; aw += w1 * v1.w;
        ax += w2 * v2.x; ay += w2 * v2.y; az += w2 * v2.z; aw += w2 * v2.w;
        ax += w3 * v3.x; ay += w3 * v3.y; az += w3 * v3.z; aw += w3 * v3.w;
    }
    for (; e + 2 <= e1; e += 2) {
        int2 p0 = csr[e + half];
        float4 v0 = *(const float4*)(Tc + (size_t)p0.x * D);
        float w0 = __int_as_float(p0.y);
        ax += w0 * v0.x; ay += w0 * v0.y; az += w0 * v0.z; aw += w0 * v0.w;
    }
    if (e < e1 && half == 0) {
        int2 p0 = csr[e];
        float4 v0 = *(const float4*)(Tc + (size_t)p0.x * D);
        float w0 = __int_as_float(p0.y);
        ax += w0 * v0.x; ay += w0 * v0.y; az += w0 * v0.z; aw += w0 * v0.w;
    }

    ax += __shfl_xor(ax, 32, 64);
    ay += __shfl_xor(ay, 32, 64);
    az += __shfl_xor(az, 32, 64);
    aw += __shfl_xor(aw, 32, 64);

    if (half == 0) {
        *(float4*)(O + (size_t)node * D + c) = make_float4(ax, ay, az, aw);
    }
}

// ---------------- launch ----------------
// out = (A^5 x)(W1 W2^4) + b2 + sum_{j=1..3}(A^j 1)(b2 W2^j) + (A^4 1)(b1 W2^4)

extern "C" void kernel_launch(void* const* d_in, const int* in_sizes, int n_in,
                              void* d_out, int out_size, void* d_ws, size_t ws_size,
                              hipStream_t stream) {
    const float* x  = (const float*)d_in[0];
    const int*   ei = (const int*)d_in[1];
    const float* W1 = (const float*)d_in[2];
    const float* b1 = (const float*)d_in[3];
    const float* W2 = (const float*)d_in[4];
    const float* b2 = (const float*)d_in[5];
    const int N = in_sizes[0] / D;
    const int E = in_sizes[1] / 2;
    float* out = (float*)d_out;

    char* ws = (char*)d_ws;
    size_t woff = 0;
    auto alloc = [&](size_t bytes) -> void* {
        void* p = ws + woff;
        woff = (woff + bytes + 15) & ~(size_t)15;
        return p;
    };
    float* T        = (float*)alloc((size_t)N * D * sizeof(float));
    int*   cnt      = (int*)  alloc((size_t)N * sizeof(int));
    int*   offsets  = (int*)  alloc((size_t)(N + 1) * sizeof(int));
    int*   rank     = (int*)  alloc((size_t)E * sizeof(int));
    float* dinv     = (float*)alloc((size_t)N * sizeof(float));
    int2*  csr      = (int2*) alloc((size_t)E * sizeof(int2));
    int*   partials = (int*)  alloc(1024 * sizeof(int));
    int*   base     = (int*)  alloc(1024 * sizeof(int));
    float* ucol     = (float*)alloc((size_t)4 * N * sizeof(float));   // [4][N]: A^j 1, j=1..4
    float* cmat     = (float*)alloc(5 * 128 * sizeof(float));         // [5][128]
    float* Wsq      = (float*)alloc(128 * 128 * sizeof(float));
    float* W4       = (float*)alloc(128 * 128 * sizeof(float));
    float* Wtot     = (float*)alloc(128 * 128 * sizeof(float));
    (void)ws_size; (void)n_in; (void)out_size;

    const int* e_src = ei;
    const int* e_dst = ei + E;
    const int NB = (N + 511) / 512;

    // --- CSR build (rank-based, no atomic in fill) ---
    k_zero<<<(N + 255) / 256, 256, 0, stream>>>(cnt, N);
    k_count<<<(E + 255) / 256, 256, 0, stream>>>(e_dst, cnt, rank, E);
    k_scanA<<<NB, 256, 0, stream>>>(cnt, partials, dinv, N);
    k_scanB<<<1, 512, 0, stream>>>(partials, base, offsets + N, NB);
    k_scanC<<<NB, 256, 0, stream>>>(cnt, base, offsets, N);
    k_fill<<<(E + 255) / 256, 256, 0, stream>>>(e_src, e_dst, rank, offsets,
                                                dinv, csr, E);

    // --- g = A^5 x, ping-pong T <-> out ---
    const int GG = (N + 3) / 4;
    k_gather<<<GG, 256, 0, stream>>>(x,   csr, offsets, dinv, T,   N);
    k_gather<<<GG, 256, 0, stream>>>(T,   csr, offsets, dinv, out, N);
    k_gather<<<GG, 256, 0, stream>>>(out, csr, offsets, dinv, T,   N);
    k_gather<<<GG, 256, 0, stream>>>(T,   csr, offsets, dinv, out, N);
    k_gather<<<GG, 256, 0, stream>>>(out, csr, offsets, dinv, T,   N);

    // --- degree vectors: ucol rows = A^j 1, j=1..4 (first call: vin = ones) ---
    k_spmv<<<(N + 255) / 256, 256, 0, stream>>>(csr, offsets, dinv, nullptr,      ucol,         N);
    k_spmv<<<(N + 255) / 256, 256, 0, stream>>>(csr, offsets, dinv, ucol,         ucol + N,     N);
    k_spmv<<<(N + 255) / 256, 256, 0, stream>>>(csr, offsets, dinv, ucol + N,     ucol + 2 * N, N);
    k_spmv<<<(N + 255) / 256, 256, 0, stream>>>(csr, offsets, dinv, ucol + 2 * N, ucol + 3 * N, N);

    // --- weight chain via squaring: Wsq = W2^2, W4 = W2^4, Wtot = W1 W2^4 ---
    k_wmm<<<128, 128, 0, stream>>>(W2, W2, Wsq);
    k_wmm<<<128, 128, 0, stream>>>(Wsq, Wsq, W4);
    k_wmm<<<128, 128, 0, stream>>>(W1, W4, Wtot);

    // --- bias rows in one block (row 4 uses precomputed W4) ---
    k_biaschain<<<1, 128, 0, stream>>>(b1, b2, W2, W4, cmat);

    // --- out = T @ Wtot + b2 + U C ---
    k_matmul<<<(N + 127) / 128, 256, 0, stream>>>(T, Wtot, out, ucol, cmat, N);
}

// Round 5
// 891.968 us; speedup vs baseline: 1.2167x; 1.0529x over previous
//
#include <hip/hip_runtime.h>
#include <hip/hip_bf16.h>

#define D 128

// ---------------- setup kernels ----------------

__global__ void k_zero(int* __restrict__ p, int n) {
    int i = blockIdx.x * 256 + threadIdx.x;
    if (i < n) p[i] = 0;
}

// count degrees AND record each edge's rank within its destination
// (rank + exclusive-scan offsets => unique dense CSR slot, no atomic in fill)
__global__ void k_count(const int* __restrict__ dst, int* __restrict__ cnt,
                        int* __restrict__ rank, int e) {
    int i = blockIdx.x * 256 + threadIdx.x;
    if (i < e) rank[i] = atomicAdd(&cnt[dst[i]], 1);
}

// ---- hierarchical scan (+ fused dinv): A) block reduce, B) scan partials, C) rescan

__global__ __launch_bounds__(256) void k_scanA(const int* __restrict__ cnt,
                                               int* __restrict__ partials,
                                               float* __restrict__ dinv, int n) {
    __shared__ int s[256];
    int b = blockIdx.x, t = threadIdx.x;
    int i0 = b * 512 + t * 2;
    int v = 0;
    if (i0 < n) {
        int c0 = cnt[i0];
        v += c0;
        dinv[i0] = 1.0f / sqrtf((float)(c0 + 2));
    }
    if (i0 + 1 < n) {
        int c1 = cnt[i0 + 1];
        v += c1;
        dinv[i0 + 1] = 1.0f / sqrtf((float)(c1 + 2));
    }
    s[t] = v;
    __syncthreads();
    for (int off = 128; off > 0; off >>= 1) {
        if (t < off) s[t] += s[t + off];
        __syncthreads();
    }
    if (t == 0) partials[b] = s[0];
}

__global__ __launch_bounds__(512) void k_scanB(const int* __restrict__ partials,
                                               int* __restrict__ base,
                                               int* __restrict__ off_n, int nb) {
    __shared__ int s[512];
    int t = threadIdx.x;
    int v = (t < nb) ? partials[t] : 0;
    s[t] = v;
    __syncthreads();
    for (int off = 1; off < 512; off <<= 1) {
        int x = (t >= off) ? s[t - off] : 0;
        __syncthreads();
        s[t] += x;
        __syncthreads();
    }
    if (t < nb) base[t] = s[t] - v;          // exclusive
    if (t == nb - 1) off_n[0] = s[t];        // total = offsets[N]
}

__global__ __launch_bounds__(256) void k_scanC(const int* __restrict__ cnt,
                                               const int* __restrict__ base,
                                               int* __restrict__ offsets, int n) {
    __shared__ int s[256];
    int b = blockIdx.x, t = threadIdx.x;
    int i0 = b * 512 + t * 2;
    int v0 = (i0 < n) ? cnt[i0] : 0;
    int v1 = (i0 + 1 < n) ? cnt[i0 + 1] : 0;
    int sum = v0 + v1;
    s[t] = sum;
    __syncthreads();
    for (int off = 1; off < 256; off <<= 1) {
        int x = (t >= off) ? s[t - off] : 0;
        __syncthreads();
        s[t] += x;
        __syncthreads();
    }
    int excl = s[t] - sum + base[b];
    if (i0 < n) offsets[i0] = excl;
    if (i0 + 1 < n) offsets[i0 + 1] = excl + v0;
}

// packed CSR entry: .x = src node, .y = bit-cast float norm. NO atomic:
// slot = offsets[dst] + precomputed rank. Streaming reads + scatter store only.
__global__ void k_fill(const int* __restrict__ src, const int* __restrict__ dst,
                       const int* __restrict__ rank, const int* __restrict__ offsets,
                       const float* __restrict__ dinv, int2* __restrict__ csr, int e) {
    int i = blockIdx.x * 256 + threadIdx.x;
    if (i < e) {
        int s = src[i];
        int d = dst[i];
        int pos = offsets[d] + rank[i];
        csr[pos] = make_int2(s, __float_as_int(dinv[s] * dinv[d]));
    }
}

// small 128x128 @ 128x128: C[r][d] = sum_k A[r][k] B[k][d]
__global__ __launch_bounds__(128) void k_wmm(const float* __restrict__ A,
                                             const float* __restrict__ B,
                                             float* __restrict__ Cm) {
    __shared__ float a[128];
    int r = blockIdx.x, d = threadIdx.x;
    a[d] = A[r * 128 + d];
    __syncthreads();
    float acc = 0.0f;
#pragma unroll 8
    for (int k = 0; k < 128; k++) acc += a[k] * B[k * 128 + d];
    Cm[r * 128 + d] = acc;
}

// blocks 0..127: Wtot = W1 @ W4.  block 128: bias row-vector chain:
// cmat rows: 0=b2, 1=b2W2, 2=b2W2^2, 3=b2W2^3, 4=b1W2^4 (uses precomputed W4)
__global__ __launch_bounds__(128) void k_wmm_bias(const float* __restrict__ W1,
                                                  const float* __restrict__ W4,
                                                  const float* __restrict__ W2,
                                                  const float* __restrict__ b1,
                                                  const float* __restrict__ b2,
                                                  float* __restrict__ Wtot,
                                                  float* __restrict__ cmat) {
    __shared__ float s[128];
    int d = threadIdx.x;
    if (blockIdx.x < 128) {
        int r = blockIdx.x;
        s[d] = W1[r * 128 + d];
        __syncthreads();
        float acc = 0.0f;
#pragma unroll 8
        for (int k = 0; k < 128; k++) acc += s[k] * W4[k * 128 + d];
        Wtot[r * 128 + d] = acc;
        return;
    }
    // bias chain block
    float v = b2[d];
    cmat[d] = v;
    for (int j = 1; j <= 3; j++) {
        s[d] = v;
        __syncthreads();
        float acc = 0.0f;
#pragma unroll 8
        for (int k = 0; k < 128; k++) acc += s[k] * W2[k * 128 + d];
        v = acc;
        cmat[j * 128 + d] = v;
        __syncthreads();
    }
    s[d] = b1[d];
    __syncthreads();
    float acc = 0.0f;
#pragma unroll 8
    for (int k = 0; k < 128; k++) acc += s[k] * W4[k * 128 + d];
    cmat[4 * 128 + d] = acc;
}

// ---------------- matmul: O = H @ W + const-bias + U C  (rank-4 + const) ----
__global__ __launch_bounds__(256) void k_matmul(const float* __restrict__ H,
                                                const float* __restrict__ W,
                                                float* __restrict__ O,
                                                const float* __restrict__ ucol,  // [4][nrows]
                                                const float* __restrict__ cmat,  // [5][128]
                                                int nrows) {
    __shared__ float Ws[32 * D];    // Ws[k][c]
    __shared__ float HsT[32 * 128]; // HsT[k][r]
    const int t = threadIdx.x;
    const int row0 = blockIdx.x * 128;
    const int tx = t & 15;    // col group (8 cols)
    const int ty = t >> 4;    // row group (8 rows)
    const int r_st = t & 127;
    const int kb = (t >> 7) * 16;   // 0 or 16
    const int gr = row0 + r_st;
    const bool grok = (gr < nrows);

    float acc[8][8];
    // constant bias row (b2)
    {
        float bc[8];
#pragma unroll
        for (int j = 0; j < 8; j++) bc[j] = cmat[tx * 8 + j];
#pragma unroll
        for (int i = 0; i < 8; i++)
#pragma unroll
            for (int j = 0; j < 8; j++) acc[i][j] = bc[j];
    }
    // rank-4 correction: ucol[tt] pairs with cmat row tt+1
#pragma unroll
    for (int tt = 0; tt < 4; tt++) {
        float c0 = cmat[(tt + 1) * D + tx * 8 + 0], c1 = cmat[(tt + 1) * D + tx * 8 + 1];
        float c2 = cmat[(tt + 1) * D + tx * 8 + 2], c3 = cmat[(tt + 1) * D + tx * 8 + 3];
        float c4 = cmat[(tt + 1) * D + tx * 8 + 4], c5 = cmat[(tt + 1) * D + tx * 8 + 5];
        float c6 = cmat[(tt + 1) * D + tx * 8 + 6], c7 = cmat[(tt + 1) * D + tx * 8 + 7];
#pragma unroll
        for (int i = 0; i < 8; i++) {
            int gr2 = row0 + ty * 8 + i;
            if (gr2 < nrows) {
                float ut = ucol[(size_t)tt * nrows + gr2];
                acc[i][0] += ut * c0; acc[i][1] += ut * c1;
                acc[i][2] += ut * c2; acc[i][3] += ut * c3;
                acc[i][4] += ut * c4; acc[i][5] += ut * c5;
                acc[i][6] += ut * c6; acc[i][7] += ut * c7;
            }
        }
    }

    float4 w0, w1, w2, w3, h0, h1, h2, h3;
    {   // prologue: load chunk 0
        const float4* W4p = (const float4*)W;
        w0 = W4p[t]; w1 = W4p[t + 256]; w2 = W4p[t + 512]; w3 = W4p[t + 768];
        if (grok) {
            const float4* Hp = (const float4*)(H + (size_t)gr * D + kb);
            h0 = Hp[0]; h1 = Hp[1]; h2 = Hp[2]; h3 = Hp[3];
        } else {
            h0 = h1 = h2 = h3 = make_float4(0.f, 0.f, 0.f, 0.f);
        }
    }

    for (int kc = 0; kc < D; kc += 32) {
        {
            float4* Ws4 = (float4*)Ws;
            Ws4[t] = w0; Ws4[t + 256] = w1; Ws4[t + 512] = w2; Ws4[t + 768] = w3;
            float vals[16];
            *(float4*)&vals[0]  = h0;
            *(float4*)&vals[4]  = h1;
            *(float4*)&vals[8]  = h2;
            *(float4*)&vals[12] = h3;
#pragma unroll
            for (int j = 0; j < 16; j++) HsT[(kb + j) * 128 + r_st] = vals[j];
        }
        __syncthreads();

        if (kc + 32 < D) {
            const float4* W4p = (const float4*)(W + (kc + 32) * D);
            w0 = W4p[t]; w1 = W4p[t + 256]; w2 = W4p[t + 512]; w3 = W4p[t + 768];
            if (grok) {
                const float4* Hp = (const float4*)(H + (size_t)gr * D + (kc + 32) + kb);
                h0 = Hp[0]; h1 = Hp[1]; h2 = Hp[2]; h3 = Hp[3];
            }
        }

#pragma unroll 8
        for (int k = 0; k < 32; k++) {
            float4 a0 = *(const float4*)&HsT[k * 128 + ty * 8];
            float4 a1 = *(const float4*)&HsT[k * 128 + ty * 8 + 4];
            float4 b0 = *(const float4*)&Ws[k * D + tx * 8];
            float4 b1 = *(const float4*)&Ws[k * D + tx * 8 + 4];
            float ar[8] = {a0.x, a0.y, a0.z, a0.w, a1.x, a1.y, a1.z, a1.w};
            float br[8] = {b0.x, b0.y, b0.z, b0.w, b1.x, b1.y, b1.z, b1.w};
#pragma unroll
            for (int i = 0; i < 8; i++)
#pragma unroll
                for (int j = 0; j < 8; j++) acc[i][j] += ar[i] * br[j];
        }
        __syncthreads();
    }
#pragma unroll
    for (int i = 0; i < 8; i++) {
        int gr2 = row0 + ty * 8 + i;
        if (gr2 < nrows) {
            float4* Op = (float4*)(O + (size_t)gr2 * D + tx * 8);
            Op[0] = make_float4(acc[i][0], acc[i][1], acc[i][2], acc[i][3]);
            Op[1] = make_float4(acc[i][4], acc[i][5], acc[i][6], acc[i][7]);
        }
    }
}

// ---------------- gather: O = A T  (+ optional fused u_out = A u_in) -------
// one wave per node; half-wave per edge row (32 lanes x float4 = 512B);
// 8-edge main loop = 4 independent 1KiB dual-row loads in flight (VGPR ~28,
// ~10 waves/SIMD; deeper ILP at lower occupancy regressed in round 3).
// WITH_U: piggyback the spmv u_out = A u_in — same operator, same csr walk;
// u loads are uniform-per-half 4B broadcasts from an L2-resident array.
template <bool WITH_U>
__global__ __launch_bounds__(256) void k_gather(const float* __restrict__ T,
                                                const int2* __restrict__ csr,
                                                const int* __restrict__ offsets,
                                                const float* __restrict__ dinv,
                                                float* __restrict__ O,
                                                const float* __restrict__ uin,
                                                float* __restrict__ uout, int n) {
    int node = blockIdx.x * 4 + (threadIdx.x >> 6);
    if (node >= n) return;
    int lane = threadIdx.x & 63;
    int half = lane >> 5;            // 0 or 1
    int c = (lane & 31) << 2;        // col base (float4)
    const float* Tc = T + c;

    float ax = 0.f, ay = 0.f, az = 0.f, aw = 0.f;
    float uacc = 0.f;
    if (half == 0) {
        float di = dinv[node];
        float sw = 2.0f * di * di;
        float4 v = *(const float4*)(Tc + (size_t)node * D);
        ax = sw * v.x; ay = sw * v.y; az = sw * v.z; aw = sw * v.w;
        if (WITH_U) uacc = sw * (uin ? uin[node] : 1.0f);
    }

    int e = offsets[node];
    const int e1 = offsets[node + 1];

    for (; e + 8 <= e1; e += 8) {
        int2 p0 = csr[e + half];
        int2 p1 = csr[e + 2 + half];
        int2 p2 = csr[e + 4 + half];
        int2 p3 = csr[e + 6 + half];
        float4 v0 = *(const float4*)(Tc + (size_t)p0.x * D);
        float4 v1 = *(const float4*)(Tc + (size_t)p1.x * D);
        float4 v2 = *(const float4*)(Tc + (size_t)p2.x * D);
        float4 v3 = *(const float4*)(Tc + (size_t)p3.x * D);
        float w0 = __int_as_float(p0.y), w1 = __int_as_float(p1.y);
        float w2 = __int_as_float(p2.y), w3 = __int_as_float(p3.y);
        if (WITH_U) {
            if (uin) {
                uacc += w0 * uin[p0.x] + w1 * uin[p1.x]
                      + w2 * uin[p2.x] + w3 * uin[p3.x];
            } else {
                uacc += w0 + w1 + w2 + w3;
            }
        }
        ax += w0 * v0.x; ay += w0 * v0.y; az += w0 * v0.z; aw += w0 * v0.w;
        ax += w1 * v1.x; ay += w1 * v1.y; az += w1 * v1.z; aw += w1 * v1.w;
        ax += w2 * v2.x; ay += w2 * v2.y; az += w2 * v2.z; aw += w2 * v2.w;
        ax += w3 * v3.x; ay += w3 * v3.y; az += w3 * v3.z; aw += w3 * v3.w;
    }
    for (; e + 2 <= e1; e += 2) {
        int2 p0 = csr[e + half];
        float4 v0 = *(const float4*)(Tc + (size_t)p0.x * D);
        float w0 = __int_as_float(p0.y);
        if (WITH_U) uacc += w0 * (uin ? uin[p0.x] : 1.0f);
        ax += w0 * v0.x; ay += w0 * v0.y; az += w0 * v0.z; aw += w0 * v0.w;
    }
    if (e < e1 && half == 0) {
        int2 p0 = csr[e];
        float4 v0 = *(const float4*)(Tc + (size_t)p0.x * D);
        float w0 = __int_as_float(p0.y);
        if (WITH_U) uacc += w0 * (uin ? uin[p0.x] : 1.0f);
        ax += w0 * v0.x; ay += w0 * v0.y; az += w0 * v0.z; aw += w0 * v0.w;
    }

    ax += __shfl_xor(ax, 32, 64);
    ay += __shfl_xor(ay, 32, 64);
    az += __shfl_xor(az, 32, 64);
    aw += __shfl_xor(aw, 32, 64);
    if (WITH_U) uacc += __shfl_xor(uacc, 32, 64);

    if (half == 0) {
        *(float4*)(O + (size_t)node * D + c) = make_float4(ax, ay, az, aw);
        if (WITH_U && lane == 0) uout[node] = uacc;
    }
}

// ---------------- launch ----------------
// out = (A^5 x)(W1 W2^4) + b2 + sum_{j=1..3}(A^j 1)(b2 W2^j) + (A^4 1)(b1 W2^4)

extern "C" void kernel_launch(void* const* d_in, const int* in_sizes, int n_in,
                              void* d_out, int out_size, void* d_ws, size_t ws_size,
                              hipStream_t stream) {
    const float* x  = (const float*)d_in[0];
    const int*   ei = (const int*)d_in[1];
    const float* W1 = (const float*)d_in[2];
    const float* b1 = (const float*)d_in[3];
    const float* W2 = (const float*)d_in[4];
    const float* b2 = (const float*)d_in[5];
    const int N = in_sizes[0] / D;
    const int E = in_sizes[1] / 2;
    float* out = (float*)d_out;

    char* ws = (char*)d_ws;
    size_t woff = 0;
    auto alloc = [&](size_t bytes) -> void* {
        void* p = ws + woff;
        woff = (woff + bytes + 15) & ~(size_t)15;
        return p;
    };
    float* T        = (float*)alloc((size_t)N * D * sizeof(float));
    int*   cnt      = (int*)  alloc((size_t)N * sizeof(int));
    int*   offsets  = (int*)  alloc((size_t)(N + 1) * sizeof(int));
    int*   rank     = (int*)  alloc((size_t)E * sizeof(int));
    float* dinv     = (float*)alloc((size_t)N * sizeof(float));
    int2*  csr      = (int2*) alloc((size_t)E * sizeof(int2));
    int*   partials = (int*)  alloc(1024 * sizeof(int));
    int*   base     = (int*)  alloc(1024 * sizeof(int));
    float* ucol     = (float*)alloc((size_t)4 * N * sizeof(float));   // [4][N]: A^j 1, j=1..4
    float* cmat     = (float*)alloc(5 * 128 * sizeof(float));         // [5][128]
    float* Wsq      = (float*)alloc(128 * 128 * sizeof(float));
    float* W4       = (float*)alloc(128 * 128 * sizeof(float));
    float* Wtot     = (float*)alloc(128 * 128 * sizeof(float));
    (void)ws_size; (void)n_in; (void)out_size;

    const int* e_src = ei;
    const int* e_dst = ei + E;
    const int NB = (N + 511) / 512;

    // --- CSR build (rank-based, no atomic in fill) ---
    k_zero<<<(N + 255) / 256, 256, 0, stream>>>(cnt, N);
    k_count<<<(E + 255) / 256, 256, 0, stream>>>(e_dst, cnt, rank, E);
    k_scanA<<<NB, 256, 0, stream>>>(cnt, partials, dinv, N);
    k_scanB<<<1, 512, 0, stream>>>(partials, base, offsets + N, NB);
    k_scanC<<<NB, 256, 0, stream>>>(cnt, base, offsets, N);
    k_fill<<<(E + 255) / 256, 256, 0, stream>>>(e_src, e_dst, rank, offsets,
                                                dinv, csr, E);

    // --- g = A^5 x, ping-pong T <-> out; u_j = A^j 1 fused into gathers 1-4 ---
    const int GG = (N + 3) / 4;
    k_gather<true ><<<GG, 256, 0, stream>>>(x,   csr, offsets, dinv, T,
                                            nullptr,      ucol,         N);
    k_gather<true ><<<GG, 256, 0, stream>>>(T,   csr, offsets, dinv, out,
                                            ucol,         ucol + N,     N);
    k_gather<true ><<<GG, 256, 0, stream>>>(out, csr, offsets, dinv, T,
                                            ucol + N,     ucol + 2 * N, N);
    k_gather<true ><<<GG, 256, 0, stream>>>(T,   csr, offsets, dinv, out,
                                            ucol + 2 * N, ucol + 3 * N, N);
    k_gather<false><<<GG, 256, 0, stream>>>(out, csr, offsets, dinv, T,
                                            nullptr,      nullptr,      N);

    // --- weight chain via squaring: Wsq = W2^2, W4 = W2^4, then
    //     [Wtot = W1 W4  ||  bias chain] in one 129-block kernel ---
    k_wmm<<<128, 128, 0, stream>>>(W2, W2, Wsq);
    k_wmm<<<128, 128, 0, stream>>>(Wsq, Wsq, W4);
    k_wmm_bias<<<129, 128, 0, stream>>>(W1, W4, W2, b1, b2, Wtot, cmat);

    // --- out = T @ Wtot + b2 + U C ---
    k_matmul<<<(N + 127) / 128, 256, 0, stream>>>(T, Wtot, out, ucol, cmat, N);
}

// Round 6
// 689.599 us; speedup vs baseline: 1.5737x; 1.2935x over previous
//
#include <hip/hip_runtime.h>
#include <hip/hip_fp16.h>

#define D 128

// ---------------- helpers ----------------

__device__ inline float4 ld_h4(const __half* p) {
    float2 raw = *(const float2*)p;                 // 8B = 4 halfs
    __half2 a = *reinterpret_cast<__half2*>(&raw.x);
    __half2 b = *reinterpret_cast<__half2*>(&raw.y);
    float2 fa = __half22float2(a), fb = __half22float2(b);
    return make_float4(fa.x, fa.y, fb.x, fb.y);
}

__device__ inline void unpack8(uint4 u, float* v) {
    const __half2* h = reinterpret_cast<const __half2*>(&u);
#pragma unroll
    for (int i = 0; i < 4; i++) {
        float2 f = __half22float2(h[i]);
        v[2 * i] = f.x; v[2 * i + 1] = f.y;
    }
}

// ---------------- setup kernels ----------------

__global__ void k_zero(int* __restrict__ p, int n) {
    int i = blockIdx.x * 256 + threadIdx.x;
    if (i < n) p[i] = 0;
}

// count degrees AND record each edge's rank within its destination
__global__ void k_count(const int* __restrict__ dst, int* __restrict__ cnt,
                        int* __restrict__ rank, int e) {
    int i = blockIdx.x * 256 + threadIdx.x;
    if (i < e) rank[i] = atomicAdd(&cnt[dst[i]], 1);
}

// f32 -> fp16 streaming convert (8 elems/thread)
__global__ void k_f2h(const float* __restrict__ in, __half* __restrict__ out, int n8) {
    int i = blockIdx.x * 256 + threadIdx.x;
    if (i < n8) {
        const float4* p = (const float4*)in + (size_t)i * 2;
        float4 a = p[0], b = p[1];
        __half2 h0 = __float22half2_rn(make_float2(a.x, a.y));
        __half2 h1 = __float22half2_rn(make_float2(a.z, a.w));
        __half2 h2 = __float22half2_rn(make_float2(b.x, b.y));
        __half2 h3 = __float22half2_rn(make_float2(b.z, b.w));
        uint4 o;
        o.x = *(unsigned*)&h0; o.y = *(unsigned*)&h1;
        o.z = *(unsigned*)&h2; o.w = *(unsigned*)&h3;
        ((uint4*)out)[i] = o;
    }
}

// ---- hierarchical scan (+ fused dinv) ----

__global__ __launch_bounds__(256) void k_scanA(const int* __restrict__ cnt,
                                               int* __restrict__ partials,
                                               float* __restrict__ dinv, int n) {
    __shared__ int s[256];
    int b = blockIdx.x, t = threadIdx.x;
    int i0 = b * 512 + t * 2;
    int v = 0;
    if (i0 < n) {
        int c0 = cnt[i0];
        v += c0;
        dinv[i0] = 1.0f / sqrtf((float)(c0 + 2));
    }
    if (i0 + 1 < n) {
        int c1 = cnt[i0 + 1];
        v += c1;
        dinv[i0 + 1] = 1.0f / sqrtf((float)(c1 + 2));
    }
    s[t] = v;
    __syncthreads();
    for (int off = 128; off > 0; off >>= 1) {
        if (t < off) s[t] += s[t + off];
        __syncthreads();
    }
    if (t == 0) partials[b] = s[0];
}

__global__ __launch_bounds__(512) void k_scanB(const int* __restrict__ partials,
                                               int* __restrict__ base,
                                               int* __restrict__ off_n, int nb) {
    __shared__ int s[512];
    int t = threadIdx.x;
    int v = (t < nb) ? partials[t] : 0;
    s[t] = v;
    __syncthreads();
    for (int off = 1; off < 512; off <<= 1) {
        int x = (t >= off) ? s[t - off] : 0;
        __syncthreads();
        s[t] += x;
        __syncthreads();
    }
    if (t < nb) base[t] = s[t] - v;          // exclusive
    if (t == nb - 1) off_n[0] = s[t];        // total = offsets[N]
}

__global__ __launch_bounds__(256) void k_scanC(const int* __restrict__ cnt,
                                               const int* __restrict__ base,
                                               int* __restrict__ offsets, int n) {
    __shared__ int s[256];
    int b = blockIdx.x, t = threadIdx.x;
    int i0 = b * 512 + t * 2;
    int v0 = (i0 < n) ? cnt[i0] : 0;
    int v1 = (i0 + 1 < n) ? cnt[i0 + 1] : 0;
    int sum = v0 + v1;
    s[t] = sum;
    __syncthreads();
    for (int off = 1; off < 256; off <<= 1) {
        int x = (t >= off) ? s[t - off] : 0;
        __syncthreads();
        s[t] += x;
        __syncthreads();
    }
    int excl = s[t] - sum + base[b];
    if (i0 < n) offsets[i0] = excl;
    if (i0 + 1 < n) offsets[i0 + 1] = excl + v0;
}

// packed CSR entry: .x = src, .y = bit-cast float norm; slot = offsets[dst]+rank
__global__ void k_fill(const int* __restrict__ src, const int* __restrict__ dst,
                       const int* __restrict__ rank, const int* __restrict__ offsets,
                       const float* __restrict__ dinv, int2* __restrict__ csr, int e) {
    int i = blockIdx.x * 256 + threadIdx.x;
    if (i < e) {
        int s = src[i];
        int d = dst[i];
        int pos = offsets[d] + rank[i];
        csr[pos] = make_int2(s, __float_as_int(dinv[s] * dinv[d]));
    }
}

// small 128x128 @ 128x128
__global__ __launch_bounds__(128) void k_wmm(const float* __restrict__ A,
                                             const float* __restrict__ B,
                                             float* __restrict__ Cm) {
    __shared__ float a[128];
    int r = blockIdx.x, d = threadIdx.x;
    a[d] = A[r * 128 + d];
    __syncthreads();
    float acc = 0.0f;
#pragma unroll 8
    for (int k = 0; k < 128; k++) acc += a[k] * B[k * 128 + d];
    Cm[r * 128 + d] = acc;
}

// blocks 0..127: Wtot = W1 @ W4.  block 128: bias chain.
__global__ __launch_bounds__(128) void k_wmm_bias(const float* __restrict__ W1,
                                                  const float* __restrict__ W4,
                                                  const float* __restrict__ W2,
                                                  const float* __restrict__ b1,
                                                  const float* __restrict__ b2,
                                                  float* __restrict__ Wtot,
                                                  float* __restrict__ cmat) {
    __shared__ float s[128];
    int d = threadIdx.x;
    if (blockIdx.x < 128) {
        int r = blockIdx.x;
        s[d] = W1[r * 128 + d];
        __syncthreads();
        float acc = 0.0f;
#pragma unroll 8
        for (int k = 0; k < 128; k++) acc += s[k] * W4[k * 128 + d];
        Wtot[r * 128 + d] = acc;
        return;
    }
    float v = b2[d];
    cmat[d] = v;
    for (int j = 1; j <= 3; j++) {
        s[d] = v;
        __syncthreads();
        float acc = 0.0f;
#pragma unroll 8
        for (int k = 0; k < 128; k++) acc += s[k] * W2[k * 128 + d];
        v = acc;
        cmat[j * 128 + d] = v;
        __syncthreads();
    }
    s[d] = b1[d];
    __syncthreads();
    float acc = 0.0f;
#pragma unroll 8
    for (int k = 0; k < 128; k++) acc += s[k] * W4[k * 128 + d];
    cmat[4 * 128 + d] = acc;
}

// ---------------- matmul: O = Hh(fp16) @ W + const-bias + U C ----------------
__global__ __launch_bounds__(256) void k_matmul(const __half* __restrict__ Hh,
                                                const float* __restrict__ W,
                                                float* __restrict__ O,
                                                const float* __restrict__ ucol,  // [4][nrows]
                                                const float* __restrict__ cmat,  // [5][128]
                                                int nrows) {
    __shared__ float Ws[32 * D];    // Ws[k][c]
    __shared__ float HsT[32 * 128]; // HsT[k][r]
    const int t = threadIdx.x;
    const int row0 = blockIdx.x * 128;
    const int tx = t & 15;
    const int ty = t >> 4;
    const int r_st = t & 127;
    const int kb = (t >> 7) * 16;   // 0 or 16
    const int gr = row0 + r_st;
    const bool grok = (gr < nrows);

    float acc[8][8];
    {
        float bc[8];
#pragma unroll
        for (int j = 0; j < 8; j++) bc[j] = cmat[tx * 8 + j];
#pragma unroll
        for (int i = 0; i < 8; i++)
#pragma unroll
            for (int j = 0; j < 8; j++) acc[i][j] = bc[j];
    }
#pragma unroll
    for (int tt = 0; tt < 4; tt++) {
        float c0 = cmat[(tt + 1) * D + tx * 8 + 0], c1 = cmat[(tt + 1) * D + tx * 8 + 1];
        float c2 = cmat[(tt + 1) * D + tx * 8 + 2], c3 = cmat[(tt + 1) * D + tx * 8 + 3];
        float c4 = cmat[(tt + 1) * D + tx * 8 + 4], c5 = cmat[(tt + 1) * D + tx * 8 + 5];
        float c6 = cmat[(tt + 1) * D + tx * 8 + 6], c7 = cmat[(tt + 1) * D + tx * 8 + 7];
#pragma unroll
        for (int i = 0; i < 8; i++) {
            int gr2 = row0 + ty * 8 + i;
            if (gr2 < nrows) {
                float ut = ucol[(size_t)tt * nrows + gr2];
                acc[i][0] += ut * c0; acc[i][1] += ut * c1;
                acc[i][2] += ut * c2; acc[i][3] += ut * c3;
                acc[i][4] += ut * c4; acc[i][5] += ut * c5;
                acc[i][6] += ut * c6; acc[i][7] += ut * c7;
            }
        }
    }

    float4 w0, w1, w2, w3;
    uint4 hp0, hp1;   // 16 halfs staged for next chunk
    {
        const float4* W4p = (const float4*)W;
        w0 = W4p[t]; w1 = W4p[t + 256]; w2 = W4p[t + 512]; w3 = W4p[t + 768];
        if (grok) {
            const uint4* Hp = (const uint4*)(Hh + (size_t)gr * D + kb);
            hp0 = Hp[0]; hp1 = Hp[1];
        } else {
            hp0 = hp1 = make_uint4(0, 0, 0, 0);
        }
    }

    for (int kc = 0; kc < D; kc += 32) {
        {
            float4* Ws4 = (float4*)Ws;
            Ws4[t] = w0; Ws4[t + 256] = w1; Ws4[t + 512] = w2; Ws4[t + 768] = w3;
            float vals[16];
            unpack8(hp0, vals);
            unpack8(hp1, vals + 8);
#pragma unroll
            for (int j = 0; j < 16; j++) HsT[(kb + j) * 128 + r_st] = vals[j];
        }
        __syncthreads();

        if (kc + 32 < D) {
            const float4* W4p = (const float4*)(W + (kc + 32) * D);
            w0 = W4p[t]; w1 = W4p[t + 256]; w2 = W4p[t + 512]; w3 = W4p[t + 768];
            if (grok) {
                const uint4* Hp = (const uint4*)(Hh + (size_t)gr * D + (kc + 32) + kb);
                hp0 = Hp[0]; hp1 = Hp[1];
            }
        }

#pragma unroll 8
        for (int k = 0; k < 32; k++) {
            float4 a0 = *(const float4*)&HsT[k * 128 + ty * 8];
            float4 a1 = *(const float4*)&HsT[k * 128 + ty * 8 + 4];
            float4 b0 = *(const float4*)&Ws[k * D + tx * 8];
            float4 b1 = *(const float4*)&Ws[k * D + tx * 8 + 4];
            float ar[8] = {a0.x, a0.y, a0.z, a0.w, a1.x, a1.y, a1.z, a1.w};
            float br[8] = {b0.x, b0.y, b0.z, b0.w, b1.x, b1.y, b1.z, b1.w};
#pragma unroll
            for (int i = 0; i < 8; i++)
#pragma unroll
                for (int j = 0; j < 8; j++) acc[i][j] += ar[i] * br[j];
        }
        __syncthreads();
    }
#pragma unroll
    for (int i = 0; i < 8; i++) {
        int gr2 = row0 + ty * 8 + i;
        if (gr2 < nrows) {
            float4* Op = (float4*)(O + (size_t)gr2 * D + tx * 8);
            Op[0] = make_float4(acc[i][0], acc[i][1], acc[i][2], acc[i][3]);
            Op[1] = make_float4(acc[i][4], acc[i][5], acc[i][6], acc[i][7]);
        }
    }
}

// ---------------- gather: O = A T (+ optional fused u_out = A u_in) --------
// fp16 rows (256B): half-wave per row = 32 lanes x 8B. f32 accumulate,
// round-nearest fp16 store. 8-edge loop = 4 independent dual-row loads.
template <bool WITH_U, bool IN_F16, bool OUT_F16>
__global__ __launch_bounds__(256) void k_gather(const void* __restrict__ Tv,
                                                const int2* __restrict__ csr,
                                                const int* __restrict__ offsets,
                                                const float* __restrict__ dinv,
                                                void* __restrict__ Ov,
                                                const float* __restrict__ uin,
                                                float* __restrict__ uout, int n) {
    int node = blockIdx.x * 4 + (threadIdx.x >> 6);
    if (node >= n) return;
    int lane = threadIdx.x & 63;
    int hf = lane >> 5;              // 0 or 1
    int c = (lane & 31) << 2;        // col base (4 cols)
    const __half* Tch = (const __half*)Tv + c;
    const float*  Tcf = (const float*)Tv + c;

    float ax = 0.f, ay = 0.f, az = 0.f, aw = 0.f;
    float uacc = 0.f;
    if (hf == 0) {
        float di = dinv[node];
        float sw = 2.0f * di * di;
        float4 v = IN_F16 ? ld_h4(Tch + (size_t)node * D)
                          : *(const float4*)(Tcf + (size_t)node * D);
        ax = sw * v.x; ay = sw * v.y; az = sw * v.z; aw = sw * v.w;
        if (WITH_U) uacc = sw * (uin ? uin[node] : 1.0f);
    }

    int e = offsets[node];
    const int e1 = offsets[node + 1];

    for (; e + 8 <= e1; e += 8) {
        int2 p0 = csr[e + hf];
        int2 p1 = csr[e + 2 + hf];
        int2 p2 = csr[e + 4 + hf];
        int2 p3 = csr[e + 6 + hf];
        float4 v0, v1, v2, v3;
        if (IN_F16) {
            v0 = ld_h4(Tch + (size_t)p0.x * D);
            v1 = ld_h4(Tch + (size_t)p1.x * D);
            v2 = ld_h4(Tch + (size_t)p2.x * D);
            v3 = ld_h4(Tch + (size_t)p3.x * D);
        } else {
            v0 = *(const float4*)(Tcf + (size_t)p0.x * D);
            v1 = *(const float4*)(Tcf + (size_t)p1.x * D);
            v2 = *(const float4*)(Tcf + (size_t)p2.x * D);
            v3 = *(const float4*)(Tcf + (size_t)p3.x * D);
        }
        float w0 = __int_as_float(p0.y), w1 = __int_as_float(p1.y);
        float w2 = __int_as_float(p2.y), w3 = __int_as_float(p3.y);
        if (WITH_U) {
            if (uin) {
                uacc += w0 * uin[p0.x] + w1 * uin[p1.x]
                      + w2 * uin[p2.x] + w3 * uin[p3.x];
            } else {
                uacc += w0 + w1 + w2 + w3;
            }
        }
        ax += w0 * v0.x; ay += w0 * v0.y; az += w0 * v0.z; aw += w0 * v0.w;
        ax += w1 * v1.x; ay += w1 * v1.y; az += w1 * v1.z; aw += w1 * v1.w;
        ax += w2 * v2.x; ay += w2 * v2.y; az += w2 * v2.z; aw += w2 * v2.w;
        ax += w3 * v3.x; ay += w3 * v3.y; az += w3 * v3.z; aw += w3 * v3.w;
    }
    for (; e + 2 <= e1; e += 2) {
        int2 p0 = csr[e + hf];
        float4 v0 = IN_F16 ? ld_h4(Tch + (size_t)p0.x * D)
                           : *(const float4*)(Tcf + (size_t)p0.x * D);
        float w0 = __int_as_float(p0.y);
        if (WITH_U) uacc += w0 * (uin ? uin[p0.x] : 1.0f);
        ax += w0 * v0.x; ay += w0 * v0.y; az += w0 * v0.z; aw += w0 * v0.w;
    }
    if (e < e1 && hf == 0) {
        int2 p0 = csr[e];
        float4 v0 = IN_F16 ? ld_h4(Tch + (size_t)p0.x * D)
                           : *(const float4*)(Tcf + (size_t)p0.x * D);
        float w0 = __int_as_float(p0.y);
        if (WITH_U) uacc += w0 * (uin ? uin[p0.x] : 1.0f);
        ax += w0 * v0.x; ay += w0 * v0.y; az += w0 * v0.z; aw += w0 * v0.w;
    }

    ax += __shfl_xor(ax, 32, 64);
    ay += __shfl_xor(ay, 32, 64);
    az += __shfl_xor(az, 32, 64);
    aw += __shfl_xor(aw, 32, 64);
    if (WITH_U) uacc += __shfl_xor(uacc, 32, 64);

    if (hf == 0) {
        if (OUT_F16) {
            __half2 o01 = __float22half2_rn(make_float2(ax, ay));
            __half2 o23 = __float22half2_rn(make_float2(az, aw));
            float2 raw;
            *(__half2*)&raw.x = o01;
            *(__half2*)&raw.y = o23;
            *(float2*)((__half*)Ov + (size_t)node * D + c) = raw;
        } else {
            *(float4*)((float*)Ov + (size_t)node * D + c) =
                make_float4(ax, ay, az, aw);
        }
        if (WITH_U && lane == 0) uout[node] = uacc;
    }
}

// ---------------- launch ----------------
// out = (A^5 x)(W1 W2^4) + b2 + sum_{j=1..3}(A^j 1)(b2 W2^j) + (A^4 1)(b1 W2^4)
// Intermediates h stored fp16 (f32 accumulate) to halve compulsory gather traffic.

extern "C" void kernel_launch(void* const* d_in, const int* in_sizes, int n_in,
                              void* d_out, int out_size, void* d_ws, size_t ws_size,
                              hipStream_t stream) {
    const float* x  = (const float*)d_in[0];
    const int*   ei = (const int*)d_in[1];
    const float* W1 = (const float*)d_in[2];
    const float* b1 = (const float*)d_in[3];
    const float* W2 = (const float*)d_in[4];
    const float* b2 = (const float*)d_in[5];
    const int N = in_sizes[0] / D;
    const int E = in_sizes[1] / 2;
    float* out = (float*)d_out;

    char* ws = (char*)d_ws;
    size_t woff = 0;
    auto alloc = [&](size_t bytes) -> void* {
        void* p = ws + woff;
        woff = (woff + bytes + 15) & ~(size_t)15;
        return p;
    };
    __half* T16a    = (__half*)alloc((size_t)N * D * sizeof(__half));
    __half* T16b    = (__half*)alloc((size_t)N * D * sizeof(__half));
    int*   cnt      = (int*)  alloc((size_t)N * sizeof(int));
    int*   offsets  = (int*)  alloc((size_t)(N + 1) * sizeof(int));
    int*   rank     = (int*)  alloc((size_t)E * sizeof(int));
    float* dinv     = (float*)alloc((size_t)N * sizeof(float));
    int2*  csr      = (int2*) alloc((size_t)E * sizeof(int2));
    int*   partials = (int*)  alloc(1024 * sizeof(int));
    int*   base     = (int*)  alloc(1024 * sizeof(int));
    float* ucol     = (float*)alloc((size_t)4 * N * sizeof(float));   // [4][N]
    float* cmat     = (float*)alloc(5 * 128 * sizeof(float));         // [5][128]
    float* Wsq      = (float*)alloc(128 * 128 * sizeof(float));
    float* W4       = (float*)alloc(128 * 128 * sizeof(float));
    float* Wtot     = (float*)alloc(128 * 128 * sizeof(float));
    // optional fp16 copy of x (only if workspace allows; else gather1 reads f32 x)
    size_t x16_bytes = (size_t)N * D * sizeof(__half);
    bool use_x16 = (woff + x16_bytes) <= ws_size;
    __half* X16 = use_x16 ? (__half*)alloc(x16_bytes) : nullptr;
    (void)n_in; (void)out_size;

    const int* e_src = ei;
    const int* e_dst = ei + E;
    const int NB = (N + 511) / 512;

    // --- CSR build (rank-based, no atomic in fill) ---
    k_zero<<<(N + 255) / 256, 256, 0, stream>>>(cnt, N);
    k_count<<<(E + 255) / 256, 256, 0, stream>>>(e_dst, cnt, rank, E);
    k_scanA<<<NB, 256, 0, stream>>>(cnt, partials, dinv, N);
    k_scanB<<<1, 512, 0, stream>>>(partials, base, offsets + N, NB);
    k_scanC<<<NB, 256, 0, stream>>>(cnt, base, offsets, N);
    k_fill<<<(E + 255) / 256, 256, 0, stream>>>(e_src, e_dst, rank, offsets,
                                                dinv, csr, E);

    // --- g = A^5 x (fp16 ping-pong); u_j = A^j 1 fused into gathers 1-4 ---
    const int GG = (N + 3) / 4;
    if (use_x16) {
        int n8 = (N * D) / 8;
        k_f2h<<<(n8 + 255) / 256, 256, 0, stream>>>(x, X16, n8);
        k_gather<true, true, true><<<GG, 256, 0, stream>>>(
            X16, csr, offsets, dinv, T16a, nullptr, ucol, N);
    } else {
        k_gather<true, false, true><<<GG, 256, 0, stream>>>(
            x, csr, offsets, dinv, T16a, nullptr, ucol, N);
    }
    k_gather<true,  true, true><<<GG, 256, 0, stream>>>(
        T16a, csr, offsets, dinv, T16b, ucol,         ucol + N,     N);
    k_gather<true,  true, true><<<GG, 256, 0, stream>>>(
        T16b, csr, offsets, dinv, T16a, ucol + N,     ucol + 2 * N, N);
    k_gather<true,  true, true><<<GG, 256, 0, stream>>>(
        T16a, csr, offsets, dinv, T16b, ucol + 2 * N, ucol + 3 * N, N);
    k_gather<false, true, true><<<GG, 256, 0, stream>>>(
        T16b, csr, offsets, dinv, T16a, nullptr,      nullptr,      N);

    // --- weight chain: Wsq = W2^2, W4 = W2^4, [Wtot = W1 W4 || bias chain] ---
    k_wmm<<<128, 128, 0, stream>>>(W2, W2, Wsq);
    k_wmm<<<128, 128, 0, stream>>>(Wsq, Wsq, W4);
    k_wmm_bias<<<129, 128, 0, stream>>>(W1, W4, W2, b1, b2, Wtot, cmat);

    // --- out = T16a @ Wtot + b2 + U C ---
    k_matmul<<<(N + 127) / 128, 256, 0, stream>>>(T16a, Wtot, out, ucol, cmat, N);
}

// Round 7
// 658.202 us; speedup vs baseline: 1.6488x; 1.0477x over previous
//
#include <hip/hip_runtime.h>
#include <hip/hip_fp16.h>

#define D 128

typedef _Float16 half8 __attribute__((ext_vector_type(8)));
typedef float floatx4 __attribute__((ext_vector_type(4)));

// ---------------- helpers ----------------

// fused f16->f32 convert + FMA (pattern-matches v_fma_mix_f32)
__device__ inline void acc_h4(float& ax, float& ay, float& az, float& aw,
                              float w, uint2 raw) {
    __half2 h01 = *reinterpret_cast<const __half2*>(&raw.x);
    __half2 h23 = *reinterpret_cast<const __half2*>(&raw.y);
    ax = fmaf(w, __low2float(h01), ax);
    ay = fmaf(w, __high2float(h01), ay);
    az = fmaf(w, __low2float(h23), az);
    aw = fmaf(w, __high2float(h23), aw);
}

// ---------------- setup kernels ----------------

__global__ void k_zero(int* __restrict__ p, int n) {
    int i = blockIdx.x * 256 + threadIdx.x;
    if (i < n) p[i] = 0;
}

// count degrees AND record each edge's rank within its destination
__global__ void k_count(const int* __restrict__ dst, int* __restrict__ cnt,
                        int* __restrict__ rank, int e) {
    int i = blockIdx.x * 256 + threadIdx.x;
    if (i < e) rank[i] = atomicAdd(&cnt[dst[i]], 1);
}

// f32 -> fp16 streaming convert (8 elems/thread)
__global__ void k_f2h(const float* __restrict__ in, __half* __restrict__ out, int n8) {
    int i = blockIdx.x * 256 + threadIdx.x;
    if (i < n8) {
        const float4* p = (const float4*)in + (size_t)i * 2;
        float4 a = p[0], b = p[1];
        __half2 h0 = __float22half2_rn(make_float2(a.x, a.y));
        __half2 h1 = __float22half2_rn(make_float2(a.z, a.w));
        __half2 h2 = __float22half2_rn(make_float2(b.x, b.y));
        __half2 h3 = __float22half2_rn(make_float2(b.z, b.w));
        uint4 o;
        o.x = *(unsigned*)&h0; o.y = *(unsigned*)&h1;
        o.z = *(unsigned*)&h2; o.w = *(unsigned*)&h3;
        ((uint4*)out)[i] = o;
    }
}

// ---- hierarchical scan (+ fused dinv) ----

__global__ __launch_bounds__(256) void k_scanA(const int* __restrict__ cnt,
                                               int* __restrict__ partials,
                                               float* __restrict__ dinv, int n) {
    __shared__ int s[256];
    int b = blockIdx.x, t = threadIdx.x;
    int i0 = b * 512 + t * 2;
    int v = 0;
    if (i0 < n) {
        int c0 = cnt[i0];
        v += c0;
        dinv[i0] = 1.0f / sqrtf((float)(c0 + 2));
    }
    if (i0 + 1 < n) {
        int c1 = cnt[i0 + 1];
        v += c1;
        dinv[i0 + 1] = 1.0f / sqrtf((float)(c1 + 2));
    }
    s[t] = v;
    __syncthreads();
    for (int off = 128; off > 0; off >>= 1) {
        if (t < off) s[t] += s[t + off];
        __syncthreads();
    }
    if (t == 0) partials[b] = s[0];
}

__global__ __launch_bounds__(512) void k_scanB(const int* __restrict__ partials,
                                               int* __restrict__ base,
                                               int* __restrict__ off_n, int nb) {
    __shared__ int s[512];
    int t = threadIdx.x;
    int v = (t < nb) ? partials[t] : 0;
    s[t] = v;
    __syncthreads();
    for (int off = 1; off < 512; off <<= 1) {
        int x = (t >= off) ? s[t - off] : 0;
        __syncthreads();
        s[t] += x;
        __syncthreads();
    }
    if (t < nb) base[t] = s[t] - v;          // exclusive
    if (t == nb - 1) off_n[0] = s[t];        // total = offsets[N]
}

__global__ __launch_bounds__(256) void k_scanC(const int* __restrict__ cnt,
                                               const int* __restrict__ base,
                                               int* __restrict__ offsets, int n) {
    __shared__ int s[256];
    int b = blockIdx.x, t = threadIdx.x;
    int i0 = b * 512 + t * 2;
    int v0 = (i0 < n) ? cnt[i0] : 0;
    int v1 = (i0 + 1 < n) ? cnt[i0 + 1] : 0;
    int sum = v0 + v1;
    s[t] = sum;
    __syncthreads();
    for (int off = 1; off < 256; off <<= 1) {
        int x = (t >= off) ? s[t - off] : 0;
        __syncthreads();
        s[t] += x;
        __syncthreads();
    }
    int excl = s[t] - sum + base[b];
    if (i0 < n) offsets[i0] = excl;
    if (i0 + 1 < n) offsets[i0 + 1] = excl + v0;
}

// packed CSR entry: .x = src, .y = bit-cast float norm; slot = offsets[dst]+rank
__global__ void k_fill(const int* __restrict__ src, const int* __restrict__ dst,
                       const int* __restrict__ rank, const int* __restrict__ offsets,
                       const float* __restrict__ dinv, int2* __restrict__ csr, int e) {
    int i = blockIdx.x * 256 + threadIdx.x;
    if (i < e) {
        int s = src[i];
        int d = dst[i];
        int pos = offsets[d] + rank[i];
        csr[pos] = make_int2(s, __float_as_int(dinv[s] * dinv[d]));
    }
}

// small 128x128 @ 128x128
__global__ __launch_bounds__(128) void k_wmm(const float* __restrict__ A,
                                             const float* __restrict__ B,
                                             float* __restrict__ Cm) {
    __shared__ float a[128];
    int r = blockIdx.x, d = threadIdx.x;
    a[d] = A[r * 128 + d];
    __syncthreads();
    float acc = 0.0f;
#pragma unroll 8
    for (int k = 0; k < 128; k++) acc += a[k] * B[k * 128 + d];
    Cm[r * 128 + d] = acc;
}

// blocks 0..127: Wtot = W1 @ W4.  block 128: bias chain.
__global__ __launch_bounds__(128) void k_wmm_bias(const float* __restrict__ W1,
                                                  const float* __restrict__ W4,
                                                  const float* __restrict__ W2,
                                                  const float* __restrict__ b1,
                                                  const float* __restrict__ b2,
                                                  float* __restrict__ Wtot,
                                                  float* __restrict__ cmat) {
    __shared__ float s[128];
    int d = threadIdx.x;
    if (blockIdx.x < 128) {
        int r = blockIdx.x;
        s[d] = W1[r * 128 + d];
        __syncthreads();
        float acc = 0.0f;
#pragma unroll 8
        for (int k = 0; k < 128; k++) acc += s[k] * W4[k * 128 + d];
        Wtot[r * 128 + d] = acc;
        return;
    }
    float v = b2[d];
    cmat[d] = v;
    for (int j = 1; j <= 3; j++) {
        s[d] = v;
        __syncthreads();
        float acc = 0.0f;
#pragma unroll 8
        for (int k = 0; k < 128; k++) acc += s[k] * W2[k * 128 + d];
        v = acc;
        cmat[j * 128 + d] = v;
        __syncthreads();
    }
    s[d] = b1[d];
    __syncthreads();
    float acc = 0.0f;
#pragma unroll 8
    for (int k = 0; k < 128; k++) acc += s[k] * W4[k * 128 + d];
    cmat[4 * 128 + d] = acc;
}

// pack Wtot into MFMA B-fragments, split hi(fp16) + lo(fp16 residual).
// frag(s,t): lane l, elem j holds W[s*32 + m(l,j)][t*16 + (l&15)] with
// m(l,j) = 8*(l>>4) + j. A-frags use the SAME m => any true HW k-permutation
// is applied consistently to A and B, so the contraction is exact regardless.
// hi at [0, 16384) halfs, lo at [16384, 32768).
__global__ __launch_bounds__(256) void k_wpack(const float* __restrict__ Wtot,
                                               __half* __restrict__ pack) {
    int tid = blockIdx.x * 256 + threadIdx.x;   // 0..2047
    int l = tid & 63, t = (tid >> 6) & 7, s = tid >> 9;
    int col = t * 16 + (l & 15);
    int krow = s * 32 + 8 * (l >> 4);
#pragma unroll
    for (int j = 0; j < 8; j++) {
        float w = Wtot[(krow + j) * 128 + col];
        __half hh = __float2half(w);
        float rem = w - __half2float(hh);
        pack[(size_t)tid * 8 + j] = hh;
        pack[16384 + (size_t)tid * 8 + j] = __float2half(rem);
    }
}

// ---------------- matmul: O = Hh(fp16) @ (Whi+Wlo) + const-bias + U C ------
// Pure-register MFMA kernel: no LDS, no syncthreads. 4 waves/block, each wave
// 16 rows x 128 cols. W fragments from L2-resident pack buffer.
__global__ __launch_bounds__(256) void k_matmul(const __half* __restrict__ Hh,
                                                const __half* __restrict__ Wpack,
                                                float* __restrict__ O,
                                                const float* __restrict__ ucol,  // [4][n]
                                                const float* __restrict__ cmat,  // [5][128]
                                                int nrows) {
    const int t = threadIdx.x;
    const int lane = t & 63, wave = t >> 6;
    const int rows0 = blockIdx.x * 64 + wave * 16;
    const int lrow = lane & 15, lk = lane >> 4;

    // epilogue u values for this lane's 4 output rows
    float uu[4][4];
#pragma unroll
    for (int r = 0; r < 4; r++) {
        int row = rows0 + lk * 4 + r;
        if (row >= nrows) row = nrows - 1;     // clamped rows never stored
#pragma unroll
        for (int tt = 0; tt < 4; tt++) uu[tt][r] = ucol[(size_t)tt * nrows + row];
    }

    floatx4 acc[8];
#pragma unroll
    for (int tl = 0; tl < 8; tl++) {
        int col = tl * 16 + lrow;
        float c0 = cmat[col];
        float c1 = cmat[128 + col], c2 = cmat[256 + col];
        float c3 = cmat[384 + col], c4 = cmat[512 + col];
#pragma unroll
        for (int r = 0; r < 4; r++)
            acc[tl][r] = c0 + uu[0][r] * c1 + uu[1][r] * c2
                            + uu[2][r] * c3 + uu[3][r] * c4;
    }

    int arow = rows0 + lrow;
    if (arow >= nrows) arow = nrows - 1;       // feeds only unstored D-rows
    const __half* abase = Hh + (size_t)arow * 128 + lk * 8;

#pragma unroll
    for (int s = 0; s < 4; s++) {
        half8 a = *reinterpret_cast<const half8*>(abase + s * 32);
        const __half* wb = Wpack + (size_t)s * 4096 + (size_t)lane * 8;
#pragma unroll
        for (int tl = 0; tl < 8; tl++) {
            half8 bh = *reinterpret_cast<const half8*>(wb + (size_t)tl * 512);
            half8 bl = *reinterpret_cast<const half8*>(wb + (size_t)tl * 512 + 16384);
            acc[tl] = __builtin_amdgcn_mfma_f32_16x16x32_f16(a, bh, acc[tl], 0, 0, 0);
            acc[tl] = __builtin_amdgcn_mfma_f32_16x16x32_f16(a, bl, acc[tl], 0, 0, 0);
        }
    }

    // C/D layout (HW-verified): col = lane&15, row = (lane>>4)*4 + reg
#pragma unroll
    for (int r = 0; r < 4; r++) {
        int row = rows0 + lk * 4 + r;
        if (row < nrows) {
            float* orow = O + (size_t)row * 128 + lrow;
#pragma unroll
            for (int tl = 0; tl < 8; tl++) orow[tl * 16] = acc[tl][r];
        }
    }
}

// ---------------- gather: O = A T (+ optional fused u_out = A u_in) --------
// fp16 rows (256B): half-wave per row = 32 lanes x 8B. f32 accumulate via
// fma_mix (convert fused into FMA), round-nearest fp16 store.
template <bool WITH_U, bool IN_F16, bool OUT_F16>
__global__ __launch_bounds__(256) void k_gather(const void* __restrict__ Tv,
                                                const int2* __restrict__ csr,
                                                const int* __restrict__ offsets,
                                                const float* __restrict__ dinv,
                                                void* __restrict__ Ov,
                                                const float* __restrict__ uin,
                                                float* __restrict__ uout, int n) {
    int node = blockIdx.x * 4 + (threadIdx.x >> 6);
    if (node >= n) return;
    int lane = threadIdx.x & 63;
    int hf = lane >> 5;              // 0 or 1
    int c = (lane & 31) << 2;        // col base (4 cols)
    const __half* Tch = (const __half*)Tv + c;
    const float*  Tcf = (const float*)Tv + c;

    float ax = 0.f, ay = 0.f, az = 0.f, aw = 0.f;
    float uacc = 0.f;
    if (hf == 0) {
        float di = dinv[node];
        float sw = 2.0f * di * di;
        if (IN_F16) {
            uint2 raw = *(const uint2*)(Tch + (size_t)node * D);
            acc_h4(ax, ay, az, aw, sw, raw);
        } else {
            float4 v = *(const float4*)(Tcf + (size_t)node * D);
            ax = sw * v.x; ay = sw * v.y; az = sw * v.z; aw = sw * v.w;
        }
        if (WITH_U) uacc = sw * (uin ? uin[node] : 1.0f);
    }

    int e = offsets[node];
    const int e1 = offsets[node + 1];

    for (; e + 8 <= e1; e += 8) {
        int2 p0 = csr[e + hf];
        int2 p1 = csr[e + 2 + hf];
        int2 p2 = csr[e + 4 + hf];
        int2 p3 = csr[e + 6 + hf];
        float w0 = __int_as_float(p0.y), w1 = __int_as_float(p1.y);
        float w2 = __int_as_float(p2.y), w3 = __int_as_float(p3.y);
        if (IN_F16) {
            uint2 r0 = *(const uint2*)(Tch + (size_t)p0.x * D);
            uint2 r1 = *(const uint2*)(Tch + (size_t)p1.x * D);
            uint2 r2 = *(const uint2*)(Tch + (size_t)p2.x * D);
            uint2 r3 = *(const uint2*)(Tch + (size_t)p3.x * D);
            if (WITH_U) {
                if (uin) {
                    uacc += w0 * uin[p0.x] + w1 * uin[p1.x]
                          + w2 * uin[p2.x] + w3 * uin[p3.x];
                } else {
                    uacc += w0 + w1 + w2 + w3;
                }
            }
            acc_h4(ax, ay, az, aw, w0, r0);
            acc_h4(ax, ay, az, aw, w1, r1);
            acc_h4(ax, ay, az, aw, w2, r2);
            acc_h4(ax, ay, az, aw, w3, r3);
        } else {
            float4 v0 = *(const float4*)(Tcf + (size_t)p0.x * D);
            float4 v1 = *(const float4*)(Tcf + (size_t)p1.x * D);
            float4 v2 = *(const float4*)(Tcf + (size_t)p2.x * D);
            float4 v3 = *(const float4*)(Tcf + (size_t)p3.x * D);
            if (WITH_U) {
                if (uin) {
                    uacc += w0 * uin[p0.x] + w1 * uin[p1.x]
                          + w2 * uin[p2.x] + w3 * uin[p3.x];
                } else {
                    uacc += w0 + w1 + w2 + w3;
                }
            }
            ax += w0 * v0.x; ay += w0 * v0.y; az += w0 * v0.z; aw += w0 * v0.w;
            ax += w1 * v1.x; ay += w1 * v1.y; az += w1 * v1.z; aw += w1 * v1.w;
            ax += w2 * v2.x; ay += w2 * v2.y; az += w2 * v2.z; aw += w2 * v2.w;
            ax += w3 * v3.x; ay += w3 * v3.y; az += w3 * v3.z; aw += w3 * v3.w;
        }
    }
    for (; e + 2 <= e1; e += 2) {
        int2 p0 = csr[e + hf];
        float w0 = __int_as_float(p0.y);
        if (WITH_U) uacc += w0 * (uin ? uin[p0.x] : 1.0f);
        if (IN_F16) {
            uint2 r0 = *(const uint2*)(Tch + (size_t)p0.x * D);
            acc_h4(ax, ay, az, aw, w0, r0);
        } else {
            float4 v0 = *(const float4*)(Tcf + (size_t)p0.x * D);
            ax += w0 * v0.x; ay += w0 * v0.y; az += w0 * v0.z; aw += w0 * v0.w;
        }
    }
    if (e < e1 && hf == 0) {
        int2 p0 = csr[e];
        float w0 = __int_as_float(p0.y);
        if (WITH_U) uacc += w0 * (uin ? uin[p0.x] : 1.0f);
        if (IN_F16) {
            uint2 r0 = *(const uint2*)(Tch + (size_t)p0.x * D);
            acc_h4(ax, ay, az, aw, w0, r0);
        } else {
            float4 v0 = *(const float4*)(Tcf + (size_t)p0.x * D);
            ax += w0 * v0.x; ay += w0 * v0.y; az += w0 * v0.z; aw += w0 * v0.w;
        }
    }

    ax += __shfl_xor(ax, 32, 64);
    ay += __shfl_xor(ay, 32, 64);
    az += __shfl_xor(az, 32, 64);
    aw += __shfl_xor(aw, 32, 64);
    if (WITH_U) uacc += __shfl_xor(uacc, 32, 64);

    if (hf == 0) {
        if (OUT_F16) {
            __half2 o01 = __float22half2_rn(make_float2(ax, ay));
            __half2 o23 = __float22half2_rn(make_float2(az, aw));
            float2 raw;
            *(__half2*)&raw.x = o01;
            *(__half2*)&raw.y = o23;
            *(float2*)((__half*)Ov + (size_t)node * D + c) = raw;
        } else {
            *(float4*)((float*)Ov + (size_t)node * D + c) =
                make_float4(ax, ay, az, aw);
        }
        if (WITH_U && lane == 0) uout[node] = uacc;
    }
}

// ---------------- launch ----------------
// out = (A^5 x)(W1 W2^4) + b2 + sum_{j=1..3}(A^j 1)(b2 W2^j) + (A^4 1)(b1 W2^4)
// Intermediates fp16 (f32 accumulate); final matmul on MFMA with W hi/lo split.

extern "C" void kernel_launch(void* const* d_in, const int* in_sizes, int n_in,
                              void* d_out, int out_size, void* d_ws, size_t ws_size,
                              hipStream_t stream) {
    const float* x  = (const float*)d_in[0];
    const int*   ei = (const int*)d_in[1];
    const float* W1 = (const float*)d_in[2];
    const float* b1 = (const float*)d_in[3];
    const float* W2 = (const float*)d_in[4];
    const float* b2 = (const float*)d_in[5];
    const int N = in_sizes[0] / D;
    const int E = in_sizes[1] / 2;
    float* out = (float*)d_out;

    char* ws = (char*)d_ws;
    size_t woff = 0;
    auto alloc = [&](size_t bytes) -> void* {
        void* p = ws + woff;
        woff = (woff + bytes + 15) & ~(size_t)15;
        return p;
    };
    __half* T16a    = (__half*)alloc((size_t)N * D * sizeof(__half));
    __half* T16b    = (__half*)alloc((size_t)N * D * sizeof(__half));
    int*   cnt      = (int*)  alloc((size_t)N * sizeof(int));
    int*   offsets  = (int*)  alloc((size_t)(N + 1) * sizeof(int));
    int*   rank     = (int*)  alloc((size_t)E * sizeof(int));
    float* dinv     = (float*)alloc((size_t)N * sizeof(float));
    int2*  csr      = (int2*) alloc((size_t)E * sizeof(int2));
    int*   partials = (int*)  alloc(1024 * sizeof(int));
    int*   base     = (int*)  alloc(1024 * sizeof(int));
    float* ucol     = (float*)alloc((size_t)4 * N * sizeof(float));   // [4][N]
    float* cmat     = (float*)alloc(5 * 128 * sizeof(float));         // [5][128]
    float* Wsq      = (float*)alloc(128 * 128 * sizeof(float));
    float* W4      = (float*)alloc(128 * 128 * sizeof(float));
    float* Wtot     = (float*)alloc(128 * 128 * sizeof(float));
    __half* Wpack   = (__half*)alloc(32768 * sizeof(__half));         // hi|lo frags
    size_t x16_bytes = (size_t)N * D * sizeof(__half);
    bool use_x16 = (woff + x16_bytes) <= ws_size;
    __half* X16 = use_x16 ? (__half*)alloc(x16_bytes) : nullptr;
    (void)n_in; (void)out_size;

    const int* e_src = ei;
    const int* e_dst = ei + E;
    const int NB = (N + 511) / 512;

    // --- CSR build (rank-based, no atomic in fill) ---
    k_zero<<<(N + 255) / 256, 256, 0, stream>>>(cnt, N);
    k_count<<<(E + 255) / 256, 256, 0, stream>>>(e_dst, cnt, rank, E);
    k_scanA<<<NB, 256, 0, stream>>>(cnt, partials, dinv, N);
    k_scanB<<<1, 512, 0, stream>>>(partials, base, offsets + N, NB);
    k_scanC<<<NB, 256, 0, stream>>>(cnt, base, offsets, N);
    k_fill<<<(E + 255) / 256, 256, 0, stream>>>(e_src, e_dst, rank, offsets,
                                                dinv, csr, E);

    // --- g = A^5 x (fp16 ping-pong); u_j = A^j 1 fused into gathers 1-4 ---
    const int GG = (N + 3) / 4;
    if (use_x16) {
        int n8 = (N * D) / 8;
        k_f2h<<<(n8 + 255) / 256, 256, 0, stream>>>(x, X16, n8);
        k_gather<true, true, true><<<GG, 256, 0, stream>>>(
            X16, csr, offsets, dinv, T16a, nullptr, ucol, N);
    } else {
        k_gather<true, false, true><<<GG, 256, 0, stream>>>(
            x, csr, offsets, dinv, T16a, nullptr, ucol, N);
    }
    k_gather<true,  true, true><<<GG, 256, 0, stream>>>(
        T16a, csr, offsets, dinv, T16b, ucol,         ucol + N,     N);
    k_gather<true,  true, true><<<GG, 256, 0, stream>>>(
        T16b, csr, offsets, dinv, T16a, ucol + N,     ucol + 2 * N, N);
    k_gather<true,  true, true><<<GG, 256, 0, stream>>>(
        T16a, csr, offsets, dinv, T16b, ucol + 2 * N, ucol + 3 * N, N);
    k_gather<false, true, true><<<GG, 256, 0, stream>>>(
        T16b, csr, offsets, dinv, T16a, nullptr,      nullptr,      N);

    // --- weight chain: Wsq = W2^2, W4 = W2^4, [Wtot = W1 W4 || bias chain],
    //     then pack Wtot into MFMA fragments (hi + residual) ---
    k_wmm<<<128, 128, 0, stream>>>(W2, W2, Wsq);
    k_wmm<<<128, 128, 0, stream>>>(Wsq, Wsq, W4);
    k_wmm_bias<<<129, 128, 0, stream>>>(W1, W4, W2, b1, b2, Wtot, cmat);
    k_wpack<<<8, 256, 0, stream>>>(Wtot, Wpack);

    // --- out = T16a @ Wtot + b2 + U C  (MFMA) ---
    k_matmul<<<(N + 63) / 64, 256, 0, stream>>>(T16a, Wpack, out, ucol, cmat, N);
}